// Round 1
// baseline (470.295 us; speedup 1.0000x reference)
//
#include <hip/hip_runtime.h>

// Problem constants (fixed by setup_inputs)
constexpr int NI = 64;    // images
constexpr int NC = 64;    // captions
constexpr int RR = 36;    // regions
constexpr int WW = 32;    // max words
constexpr int DI = 2048;  // img_dim
constexpr int DD = 1024;  // d
constexpr int MROWS = NI * RR;  // 2304
constexpr int NCOLS = NC * WW;  // 2048

#define EPSV 1e-8f
#define LAM_SM 9.0f
#define LAM_LSE 6.0f
#define LEAKY_S 0.1f

// ---------------- GEMM 1: proj = images @ W_fc + b_fc ----------------
// A (2304 x 2048) row-major, B (2048 x 1024) row-major, C (2304 x 1024)
__global__ __launch_bounds__(256) void gemm_proj(const float* __restrict__ A,
                                                 const float* __restrict__ B,
                                                 const float* __restrict__ bias,
                                                 float* __restrict__ C)
{
    __shared__ float As[16][68];  // [k][m]
    __shared__ float Bs[16][68];  // [k][n]
    const int bm = blockIdx.x * 64;
    const int bn = blockIdx.y * 64;
    const int tid = threadIdx.x;
    const int tx = tid & 15, ty = tid >> 4;
    float acc[4][4] = {};

    for (int k0 = 0; k0 < DI; k0 += 16) {
        // A tile 64 rows x 16 k, stored transposed As[k][m]
        {
            int row = tid >> 2, kq = (tid & 3) * 4;
            float4 v = *reinterpret_cast<const float4*>(&A[(bm + row) * DI + k0 + kq]);
            As[kq + 0][row] = v.x; As[kq + 1][row] = v.y;
            As[kq + 2][row] = v.z; As[kq + 3][row] = v.w;
        }
        // B tile 16 k x 64 n, natural layout Bs[k][n]
        {
            int k = tid >> 4, n4 = (tid & 15) * 4;
            float4 v = *reinterpret_cast<const float4*>(&B[(k0 + k) * DD + bn + n4]);
            *reinterpret_cast<float4*>(&Bs[k][n4]) = v;
        }
        __syncthreads();
        #pragma unroll
        for (int k = 0; k < 16; ++k) {
            float a[4], b[4];
            #pragma unroll
            for (int j = 0; j < 4; ++j) a[j] = As[k][ty * 4 + j];
            #pragma unroll
            for (int j = 0; j < 4; ++j) b[j] = Bs[k][tx * 4 + j];
            #pragma unroll
            for (int i = 0; i < 4; ++i)
                #pragma unroll
                for (int j = 0; j < 4; ++j) acc[i][j] += a[i] * b[j];
        }
        __syncthreads();
    }
    #pragma unroll
    for (int i = 0; i < 4; ++i) {
        int row = bm + ty * 4 + i;
        #pragma unroll
        for (int j = 0; j < 4; ++j) {
            int col = bn + tx * 4 + j;
            C[row * DD + col] = acc[i][j] + bias[col];
        }
    }
}

// ---------------- row l2norm in place (rows of length 1024) ----------------
__global__ __launch_bounds__(256) void rownorm_1024(float* __restrict__ X)
{
    const int row = blockIdx.x;
    float4 v = *reinterpret_cast<float4*>(&X[row * 1024 + threadIdx.x * 4]);
    float s = v.x * v.x + v.y * v.y + v.z * v.z + v.w * v.w;
    #pragma unroll
    for (int off = 32; off; off >>= 1) s += __shfl_down(s, off);
    __shared__ float ps[4];
    if ((threadIdx.x & 63) == 0) ps[threadIdx.x >> 6] = s;
    __syncthreads();
    float tot = ps[0] + ps[1] + ps[2] + ps[3];
    float inv = 1.0f / (sqrtf(tot) + EPSV);
    v.x *= inv; v.y *= inv; v.z *= inv; v.w *= inv;
    *reinterpret_cast<float4*>(&X[row * 1024 + threadIdx.x * 4]) = v;
}

// ---------------- caption norm: Y = l2norm(X), w1 = ||Y|| ----------------
__global__ __launch_bounds__(256) void capnorm(const float* __restrict__ X,
                                               float* __restrict__ Y,
                                               float* __restrict__ w1)
{
    const int row = blockIdx.x;
    float4 v = *reinterpret_cast<const float4*>(&X[row * 1024 + threadIdx.x * 4]);
    float s = v.x * v.x + v.y * v.y + v.z * v.z + v.w * v.w;
    #pragma unroll
    for (int off = 32; off; off >>= 1) s += __shfl_down(s, off);
    __shared__ float ps[4];
    if ((threadIdx.x & 63) == 0) ps[threadIdx.x >> 6] = s;
    __syncthreads();
    float tot = ps[0] + ps[1] + ps[2] + ps[3];
    float n = sqrtf(tot);
    float inv = 1.0f / (n + EPSV);
    v.x *= inv; v.y *= inv; v.z *= inv; v.w *= inv;
    *reinterpret_cast<float4*>(&Y[row * 1024 + threadIdx.x * 4]) = v;
    if (threadIdx.x == 0) w1[row] = n * inv;  // = n/(n+EPS) = ||normalized||
}

// ---------------- GEMM 2 (NT): S = img_emb @ capn^T ----------------
// A (2304 x 1024) row-major, B (2048 x 1024) row-major, S (2304 x 2048)
__global__ __launch_bounds__(256) void gemm_nt(const float* __restrict__ A,
                                               const float* __restrict__ B,
                                               float* __restrict__ S)
{
    __shared__ float As[16][68];  // [k][m]
    __shared__ float Bs[16][68];  // [k][n]
    const int bm = blockIdx.x * 64;
    const int bn = blockIdx.y * 64;
    const int tid = threadIdx.x;
    const int tx = tid & 15, ty = tid >> 4;
    float acc[4][4] = {};

    for (int k0 = 0; k0 < DD; k0 += 16) {
        int row = tid >> 2, kq = (tid & 3) * 4;
        float4 va = *reinterpret_cast<const float4*>(&A[(bm + row) * DD + k0 + kq]);
        As[kq + 0][row] = va.x; As[kq + 1][row] = va.y;
        As[kq + 2][row] = va.z; As[kq + 3][row] = va.w;
        float4 vb = *reinterpret_cast<const float4*>(&B[(bn + row) * DD + k0 + kq]);
        Bs[kq + 0][row] = vb.x; Bs[kq + 1][row] = vb.y;
        Bs[kq + 2][row] = vb.z; Bs[kq + 3][row] = vb.w;
        __syncthreads();
        #pragma unroll
        for (int k = 0; k < 16; ++k) {
            float a[4], b[4];
            #pragma unroll
            for (int j = 0; j < 4; ++j) a[j] = As[k][ty * 4 + j];
            #pragma unroll
            for (int j = 0; j < 4; ++j) b[j] = Bs[k][tx * 4 + j];
            #pragma unroll
            for (int i = 0; i < 4; ++i)
                #pragma unroll
                for (int j = 0; j < 4; ++j) acc[i][j] += a[i] * b[j];
        }
        __syncthreads();
    }
    #pragma unroll
    for (int i = 0; i < 4; ++i)
        #pragma unroll
        for (int j = 0; j < 4; ++j)
            S[(bm + ty * 4 + i) * NCOLS + bn + tx * 4 + j] = acc[i][j];
}

// ---------------- per-image Gram: G[i][r][r'] = <emb[i,r], emb[i,r']> ----------------
// one wave per (i, r) row
__global__ __launch_bounds__(64) void gram_rows(const float* __restrict__ emb,
                                                float* __restrict__ G)
{
    const int b = blockIdx.x;         // 0..2303
    const int i = b / RR, r = b % RR;
    const int lane = threadIdx.x;     // 0..63
    float a[16];
    const float* rowp = &emb[(i * RR + r) * DD + lane * 16];
    #pragma unroll
    for (int q = 0; q < 4; ++q) {
        float4 v = *reinterpret_cast<const float4*>(&rowp[q * 4]);
        a[q * 4 + 0] = v.x; a[q * 4 + 1] = v.y; a[q * 4 + 2] = v.z; a[q * 4 + 3] = v.w;
    }
    for (int rp = 0; rp < RR; ++rp) {
        const float* bp = &emb[(i * RR + rp) * DD + lane * 16];
        float s = 0.f;
        #pragma unroll
        for (int q = 0; q < 4; ++q) {
            float4 v = *reinterpret_cast<const float4*>(&bp[q * 4]);
            s += a[q * 4 + 0] * v.x + a[q * 4 + 1] * v.y + a[q * 4 + 2] * v.z + a[q * 4 + 3] * v.w;
        }
        #pragma unroll
        for (int off = 32; off; off >>= 1) s += __shfl_xor(s, off);
        if (lane == 0) G[(i * RR + r) * RR + rp] = s;
    }
}

// ---------------- fused epilogue per (c, i) ----------------
__global__ __launch_bounds__(256) void epilogue(const float* __restrict__ S,
                                                const float* __restrict__ G,
                                                const float* __restrict__ w1v,
                                                const int* __restrict__ cap_lens,
                                                float* __restrict__ out)
{
    const int c = blockIdx.x, i = blockIdx.y;
    const int tid = threadIdx.x;
    __shared__ float Sl[RR][33];
    __shared__ float A1[RR][33];
    __shared__ float A2[WW][40];
    __shared__ float Gl[RR][37];
    __shared__ float Tl[WW][RR];
    __shared__ float w12s[WW];
    __shared__ float ew[WW];
    const int len = cap_lens[c];

    for (int e = tid; e < RR * WW; e += 256) {
        int r = e >> 5, w = e & 31;
        Sl[r][w] = S[(i * RR + r) * NCOLS + c * WW + w];
    }
    for (int e = tid; e < RR * RR; e += 256) {
        int r = e / RR, rp = e % RR;
        Gl[r][rp] = G[(i * RR + r) * RR + rp];
    }
    __syncthreads();

    // P1: per region row r: leaky, mask, l2norm over words
    if (tid < RR) {
        int r = tid;
        float ss = 0.f;
        #pragma unroll
        for (int w = 0; w < WW; ++w) {
            float v = Sl[r][w];
            v = v > 0.f ? v : LEAKY_S * v;
            v = (w < len) ? v : 0.f;
            ss += v * v;
        }
        float inv = 1.0f / (sqrtf(ss) + EPSV);
        #pragma unroll
        for (int w = 0; w < WW; ++w) {
            float v = Sl[r][w];
            v = v > 0.f ? v : LEAKY_S * v;
            v = (w < len) ? v : 0.f;
            A1[r][w] = v * inv;
        }
    }
    __syncthreads();

    // P2: per word w: softmax over regions (temp 9), and w12 = sum_r attn*S
    if (tid < WW) {
        int w = tid;
        float m = -1e30f;
        for (int r = 0; r < RR; ++r) m = fmaxf(m, A1[r][w]);
        float sum = 0.f;
        for (int r = 0; r < RR; ++r) {
            float e = __expf(LAM_SM * (A1[r][w] - m));
            A2[w][r] = e; sum += e;
        }
        float inv = 1.0f / sum;
        float w12 = 0.f;
        for (int r = 0; r < RR; ++r) {
            float a = A2[w][r] * inv;
            A2[w][r] = a;
            w12 += a * Sl[r][w];
        }
        w12s[w] = w12;
    }
    __syncthreads();

    // P3: t[w][r] = sum_rp attn[w][rp] * G[r][rp]
    for (int e = tid; e < WW * RR; e += 256) {
        int w = e / RR, r = e % RR;
        float t = 0.f;
        for (int rp = 0; rp < RR; ++rp) t += A2[w][rp] * Gl[r][rp];
        Tl[w][r] = t;
    }
    __syncthreads();

    // P4: per word: w2 = sqrt(attn^T G attn), row_sim, exp term
    if (tid < WW) {
        int w = tid;
        float w2sq = 0.f;
        for (int r = 0; r < RR; ++r) w2sq += A2[w][r] * Tl[w][r];
        float w2 = sqrtf(fmaxf(w2sq, 0.f));
        float denom = fmaxf(w1v[c * WW + w] * w2, EPSV);
        float rs = w12s[w] / denom;
        ew[w] = (w < len) ? __expf(LAM_LSE * rs) : 0.f;
    }
    __syncthreads();

    // P5: LSE over words -> out[i][c]
    if (tid == 0) {
        float s = 0.f;
        for (int w = 0; w < WW; ++w) s += ew[w];
        out[i * NC + c] = logf(s) / LAM_LSE;
    }
}

extern "C" void kernel_launch(void* const* d_in, const int* in_sizes, int n_in,
                              void* d_out, int out_size, void* d_ws, size_t ws_size,
                              hipStream_t stream)
{
    const float* images  = (const float*)d_in[0];
    const float* cap_emb = (const float*)d_in[1];
    const float* W_fc    = (const float*)d_in[2];
    const float* b_fc    = (const float*)d_in[3];
    const int*   cap_lens = (const int*)d_in[4];
    float* out = (float*)d_out;

    char* ws = (char*)d_ws;
    float* img_emb = (float*)(ws);                 //  9,437,184 B (2304x1024)
    float* capn    = (float*)(ws + 9437184);       //  8,388,608 B (2048x1024)
    float* S       = (float*)(ws + 17825792);      // 18,874,368 B (2304x2048)
    float* G       = (float*)(ws + 36700160);      //    331,776 B (64x36x36)
    float* w1      = (float*)(ws + 37031936);      //      8,192 B (2048)

    gemm_proj<<<dim3(MROWS / 64, DD / 64), 256, 0, stream>>>(images, W_fc, b_fc, img_emb);
    rownorm_1024<<<MROWS, 256, 0, stream>>>(img_emb);
    capnorm<<<NCOLS, 256, 0, stream>>>(cap_emb, capn, w1);
    gemm_nt<<<dim3(MROWS / 64, NCOLS / 64), 256, 0, stream>>>(img_emb, capn, S);
    gram_rows<<<MROWS, 64, 0, stream>>>(img_emb, G);
    epilogue<<<dim3(NC, NI), 256, 0, stream>>>(S, G, w1, cap_lens, out);
}

// Round 2
// 216.071 us; speedup vs baseline: 2.1766x; 2.1766x over previous
//
#include <hip/hip_runtime.h>

// Problem constants (fixed by setup_inputs)
constexpr int NI = 64;    // images
constexpr int NC = 64;    // captions
constexpr int RR = 36;    // regions
constexpr int WW = 32;    // max words
constexpr int DI = 2048;  // img_dim
constexpr int DD = 1024;  // d
constexpr int MROWS = NI * RR;  // 2304
constexpr int NCOLS = NC * WW;  // 2048

#define EPSV 1e-8f
#define LAM_SM 9.0f
#define LAM_LSE 6.0f
#define LEAKY_S 0.1f

typedef __bf16 bf16x8 __attribute__((ext_vector_type(8)));
typedef float f32x4 __attribute__((ext_vector_type(4)));
typedef unsigned short ushort8v __attribute__((ext_vector_type(8)));
typedef unsigned short ushort4v __attribute__((ext_vector_type(4)));

__device__ __forceinline__ unsigned short f2bf(float f) {
    unsigned int u = __builtin_bit_cast(unsigned int, f);
    unsigned int r = (u + 0x7fffu + ((u >> 16) & 1u)) >> 16;
    return (unsigned short)r;
}

#define GLOAD16(gp, lp)                                                              \
    __builtin_amdgcn_global_load_lds(                                                \
        (const __attribute__((address_space(1))) unsigned int*)(gp),                 \
        (__attribute__((address_space(3))) unsigned int*)(lp), 16, 0, 0)

// ---------------- f32 -> bf16 bulk convert (8 elems/thread) ----------------
__global__ __launch_bounds__(256) void cvt_bf16(const float* __restrict__ X,
                                                unsigned short* __restrict__ Y, int n8)
{
    int i = blockIdx.x * 256 + threadIdx.x;
    if (i >= n8) return;
    const float4* X4 = reinterpret_cast<const float4*>(X);
    float4 a = X4[i * 2], b = X4[i * 2 + 1];
    ushort8v o;
    o[0] = f2bf(a.x); o[1] = f2bf(a.y); o[2] = f2bf(a.z); o[3] = f2bf(a.w);
    o[4] = f2bf(b.x); o[5] = f2bf(b.y); o[6] = f2bf(b.z); o[7] = f2bf(b.w);
    *reinterpret_cast<ushort8v*>(&Y[i * 8]) = o;
}

// ---------------- W_fc (2048x1024) f32 -> Wt (1024x2048) bf16 ----------------
__global__ __launch_bounds__(256) void transpose_cvt(const float* __restrict__ W,
                                                     unsigned short* __restrict__ Wt)
{
    __shared__ float t[32][33];
    const int bk = blockIdx.x * 32;  // k dim (2048)
    const int bn = blockIdx.y * 32;  // n dim (1024)
    const int x = threadIdx.x;       // 0..31
    for (int yy = threadIdx.y; yy < 32; yy += 8)
        t[yy][x] = W[(bk + yy) * DD + bn + x];
    __syncthreads();
    for (int yy = threadIdx.y; yy < 32; yy += 8)
        Wt[(bn + yy) * DI + bk + x] = f2bf(t[x][yy]);
}

// ---------------- MFMA GEMM: C(MxN f32) = A(MxK bf16) @ Bt(NxK bf16)^T [+bias] ----------------
// m97 structure: 128x128 tile, 4 waves (2x2), each wave 64x64 = 4x4 frags of 16x16x32.
template <int M, int N, int K, bool BIAS>
__global__ __launch_bounds__(256) void gemm_mfma(const unsigned short* __restrict__ A,
                                                 const unsigned short* __restrict__ Bt,
                                                 const float* __restrict__ bias,
                                                 float* __restrict__ C)
{
    __shared__ __align__(16) unsigned short As[128 * 32];
    __shared__ __align__(16) unsigned short Bs[128 * 32];
    const int tid = threadIdx.x;
    const int w = tid >> 6, lane = tid & 63;
    const int bm = blockIdx.x * 128, bn = blockIdx.y * 128;
    const int wr = w >> 1, wc = w & 1;

    f32x4 acc[4][4] = {};

    // staging: wave w stages rows [w*32, w*32+32) in two 16-row loads
    const int sr = w * 32 + (lane >> 2);
    const int sk = (lane & 3) * 8;
    const unsigned short* gA0 = &A[(bm + sr) * K + sk];
    const unsigned short* gB0 = &Bt[(bn + sr) * K + sk];
    unsigned short* lA0 = &As[w * 1024];
    unsigned short* lB0 = &Bs[w * 1024];

    const int kgrp = (lane >> 4) * 8;
    const int fr = lane & 15;

    for (int k0 = 0; k0 < K; k0 += 32) {
        __syncthreads();
        GLOAD16(gA0 + k0, lA0);
        GLOAD16(gA0 + 16 * K + k0, lA0 + 512);
        GLOAD16(gB0 + k0, lB0);
        GLOAD16(gB0 + 16 * K + k0, lB0 + 512);
        __syncthreads();

        bf16x8 af[4], bf[4];
        #pragma unroll
        for (int mi = 0; mi < 4; ++mi)
            af[mi] = *reinterpret_cast<const bf16x8*>(&As[(wr * 64 + mi * 16 + fr) * 32 + kgrp]);
        #pragma unroll
        for (int ni = 0; ni < 4; ++ni)
            bf[ni] = *reinterpret_cast<const bf16x8*>(&Bs[(wc * 64 + ni * 16 + fr) * 32 + kgrp]);
        #pragma unroll
        for (int mi = 0; mi < 4; ++mi)
            #pragma unroll
            for (int ni = 0; ni < 4; ++ni)
                acc[mi][ni] = __builtin_amdgcn_mfma_f32_16x16x32_bf16(af[mi], bf[ni], acc[mi][ni], 0, 0, 0);
    }

    // C/D layout: col = lane&15, row = (lane>>4)*4 + reg  [m89 verified]
    const int cr0 = (lane >> 4) * 4, cc = lane & 15;
    #pragma unroll
    for (int mi = 0; mi < 4; ++mi) {
        int row0 = bm + wr * 64 + mi * 16 + cr0;
        #pragma unroll
        for (int ni = 0; ni < 4; ++ni) {
            int col = bn + wc * 64 + ni * 16 + cc;
            float bv = BIAS ? bias[col] : 0.f;
            #pragma unroll
            for (int r = 0; r < 4; ++r)
                C[(row0 + r) * N + col] = acc[mi][ni][r] + bv;
        }
    }
}

// ---------------- row l2norm in place + bf16 copy (rows of length 1024) ----------------
__global__ __launch_bounds__(256) void rownorm_1024_bf(float* __restrict__ X,
                                                       unsigned short* __restrict__ Xbf)
{
    const int row = blockIdx.x;
    float4 v = *reinterpret_cast<float4*>(&X[row * 1024 + threadIdx.x * 4]);
    float s = v.x * v.x + v.y * v.y + v.z * v.z + v.w * v.w;
    #pragma unroll
    for (int off = 32; off; off >>= 1) s += __shfl_down(s, off);
    __shared__ float ps[4];
    if ((threadIdx.x & 63) == 0) ps[threadIdx.x >> 6] = s;
    __syncthreads();
    float tot = ps[0] + ps[1] + ps[2] + ps[3];
    float inv = 1.0f / (sqrtf(tot) + EPSV);
    v.x *= inv; v.y *= inv; v.z *= inv; v.w *= inv;
    *reinterpret_cast<float4*>(&X[row * 1024 + threadIdx.x * 4]) = v;
    ushort4v o;
    o[0] = f2bf(v.x); o[1] = f2bf(v.y); o[2] = f2bf(v.z); o[3] = f2bf(v.w);
    *reinterpret_cast<ushort4v*>(&Xbf[row * 1024 + threadIdx.x * 4]) = o;
}

// ---------------- caption norm: Ybf = bf16(l2norm(X)), w1 = ||l2norm(X)|| ----------------
__global__ __launch_bounds__(256) void capnorm_bf(const float* __restrict__ X,
                                                  unsigned short* __restrict__ Ybf,
                                                  float* __restrict__ w1)
{
    const int row = blockIdx.x;
    float4 v = *reinterpret_cast<const float4*>(&X[row * 1024 + threadIdx.x * 4]);
    float s = v.x * v.x + v.y * v.y + v.z * v.z + v.w * v.w;
    #pragma unroll
    for (int off = 32; off; off >>= 1) s += __shfl_down(s, off);
    __shared__ float ps[4];
    if ((threadIdx.x & 63) == 0) ps[threadIdx.x >> 6] = s;
    __syncthreads();
    float tot = ps[0] + ps[1] + ps[2] + ps[3];
    float n = sqrtf(tot);
    float inv = 1.0f / (n + EPSV);
    v.x *= inv; v.y *= inv; v.z *= inv; v.w *= inv;
    ushort4v o;
    o[0] = f2bf(v.x); o[1] = f2bf(v.y); o[2] = f2bf(v.z); o[3] = f2bf(v.w);
    *reinterpret_cast<ushort4v*>(&Ybf[row * 1024 + threadIdx.x * 4]) = o;
    if (threadIdx.x == 0) w1[row] = n * inv;  // = ||normalized||
}

// ---------------- per-image Gram: G[i][r][r'] = <emb[i,r], emb[i,r']> ----------------
__global__ __launch_bounds__(64) void gram_rows(const float* __restrict__ emb,
                                                float* __restrict__ G)
{
    const int b = blockIdx.x;         // 0..2303
    const int i = b / RR, r = b % RR;
    const int lane = threadIdx.x;     // 0..63
    float a[16];
    const float* rowp = &emb[(i * RR + r) * DD + lane * 16];
    #pragma unroll
    for (int q = 0; q < 4; ++q) {
        float4 v = *reinterpret_cast<const float4*>(&rowp[q * 4]);
        a[q * 4 + 0] = v.x; a[q * 4 + 1] = v.y; a[q * 4 + 2] = v.z; a[q * 4 + 3] = v.w;
    }
    for (int rp = 0; rp < RR; ++rp) {
        const float* bp = &emb[(i * RR + rp) * DD + lane * 16];
        float s = 0.f;
        #pragma unroll
        for (int q = 0; q < 4; ++q) {
            float4 v = *reinterpret_cast<const float4*>(&bp[q * 4]);
            s += a[q * 4 + 0] * v.x + a[q * 4 + 1] * v.y + a[q * 4 + 2] * v.z + a[q * 4 + 3] * v.w;
        }
        #pragma unroll
        for (int off = 32; off; off >>= 1) s += __shfl_xor(s, off);
        if (lane == 0) G[(i * RR + r) * RR + rp] = s;
    }
}

// ---------------- fused epilogue per (c, i) ----------------
__global__ __launch_bounds__(256) void epilogue(const float* __restrict__ S,
                                                const float* __restrict__ G,
                                                const float* __restrict__ w1v,
                                                const int* __restrict__ cap_lens,
                                                float* __restrict__ out)
{
    const int c = blockIdx.x, i = blockIdx.y;
    const int tid = threadIdx.x;
    __shared__ float Sl[RR][33];
    __shared__ float A1[RR][33];
    __shared__ float A2[WW][40];
    __shared__ float Gl[RR][37];
    __shared__ float Tl[WW][RR];
    __shared__ float w12s[WW];
    __shared__ float ew[WW];
    const int len = cap_lens[c];

    for (int e = tid; e < RR * WW; e += 256) {
        int r = e >> 5, w = e & 31;
        Sl[r][w] = S[(i * RR + r) * NCOLS + c * WW + w];
    }
    for (int e = tid; e < RR * RR; e += 256) {
        int r = e / RR, rp = e % RR;
        Gl[r][rp] = G[(i * RR + r) * RR + rp];
    }
    __syncthreads();

    // P1: per region row r: leaky, mask, l2norm over words
    if (tid < RR) {
        int r = tid;
        float ss = 0.f;
        #pragma unroll
        for (int w = 0; w < WW; ++w) {
            float v = Sl[r][w];
            v = v > 0.f ? v : LEAKY_S * v;
            v = (w < len) ? v : 0.f;
            ss += v * v;
        }
        float inv = 1.0f / (sqrtf(ss) + EPSV);
        #pragma unroll
        for (int w = 0; w < WW; ++w) {
            float v = Sl[r][w];
            v = v > 0.f ? v : LEAKY_S * v;
            v = (w < len) ? v : 0.f;
            A1[r][w] = v * inv;
        }
    }
    __syncthreads();

    // P2: per word w: softmax over regions (temp 9), and w12 = sum_r attn*S
    if (tid < WW) {
        int w = tid;
        float m = -1e30f;
        for (int r = 0; r < RR; ++r) m = fmaxf(m, A1[r][w]);
        float sum = 0.f;
        for (int r = 0; r < RR; ++r) {
            float e = __expf(LAM_SM * (A1[r][w] - m));
            A2[w][r] = e; sum += e;
        }
        float inv = 1.0f / sum;
        float w12 = 0.f;
        for (int r = 0; r < RR; ++r) {
            float a = A2[w][r] * inv;
            A2[w][r] = a;
            w12 += a * Sl[r][w];
        }
        w12s[w] = w12;
    }
    __syncthreads();

    // P3: t[w][r] = sum_rp attn[w][rp] * G[r][rp]
    for (int e = tid; e < WW * RR; e += 256) {
        int w = e / RR, r = e % RR;
        float t = 0.f;
        for (int rp = 0; rp < RR; ++rp) t += A2[w][rp] * Gl[r][rp];
        Tl[w][r] = t;
    }
    __syncthreads();

    // P4: per word: w2 = sqrt(attn^T G attn), row_sim, exp term
    if (tid < WW) {
        int w = tid;
        float w2sq = 0.f;
        for (int r = 0; r < RR; ++r) w2sq += A2[w][r] * Tl[w][r];
        float w2 = sqrtf(fmaxf(w2sq, 0.f));
        float denom = fmaxf(w1v[c * WW + w] * w2, EPSV);
        float rs = w12s[w] / denom;
        ew[w] = (w < len) ? __expf(LAM_LSE * rs) : 0.f;
    }
    __syncthreads();

    // P5: LSE over words -> out[i][c]
    if (tid == 0) {
        float s = 0.f;
        for (int w = 0; w < WW; ++w) s += ew[w];
        out[i * NC + c] = logf(s) / LAM_LSE;
    }
}

extern "C" void kernel_launch(void* const* d_in, const int* in_sizes, int n_in,
                              void* d_out, int out_size, void* d_ws, size_t ws_size,
                              hipStream_t stream)
{
    const float* images   = (const float*)d_in[0];
    const float* cap_emb  = (const float*)d_in[1];
    const float* W_fc     = (const float*)d_in[2];
    const float* b_fc     = (const float*)d_in[3];
    const int*   cap_lens = (const int*)d_in[4];
    float* out = (float*)d_out;

    char* ws = (char*)d_ws;
    // layout (bytes):
    float*          img_emb   = (float*)(ws);                        // 9,437,184
    // region A (18,874,368 B): images_bf + Wt during gemm_proj, then S
    unsigned short* images_bf = (unsigned short*)(ws + 9437184);     // 9,437,184
    unsigned short* Wt        = (unsigned short*)(ws + 18874368);    // 4,194,304
    float*          S         = (float*)(ws + 9437184);              // reuses region A
    unsigned short* img_bf    = (unsigned short*)(ws + 28311552);    // 4,718,592
    unsigned short* capn_bf   = (unsigned short*)(ws + 33030144);    // 4,194,304
    float*          G         = (float*)(ws + 37224448);             //   331,776
    float*          w1        = (float*)(ws + 37556224);             //     8,192

    // 1. images f32 -> bf16 (4,718,592 elems / 8)
    cvt_bf16<<<MROWS * DI / 2048, 256, 0, stream>>>(images, images_bf, MROWS * DI / 8);
    // 2. W_fc (2048x1024) -> Wt (1024x2048) bf16
    transpose_cvt<<<dim3(DI / 32, DD / 32), dim3(32, 8), 0, stream>>>(W_fc, Wt);
    // 3. img_emb = images @ W_fc + b_fc   (MFMA)
    gemm_mfma<MROWS, DD, DI, true><<<dim3(MROWS / 128, DD / 128), 256, 0, stream>>>(images_bf, Wt, b_fc, img_emb);
    // 4. l2norm rows of img_emb (f32 in place) + bf16 copy
    rownorm_1024_bf<<<MROWS, 256, 0, stream>>>(img_emb, img_bf);
    // 5. cap_emb -> l2norm -> bf16 + w1
    capnorm_bf<<<NCOLS, 256, 0, stream>>>(cap_emb, capn_bf, w1);
    // 6. S = img_emb @ capn^T  (MFMA; overwrites images_bf/Wt region)
    gemm_mfma<MROWS, NCOLS, DD, false><<<dim3(MROWS / 128, NCOLS / 128), 256, 0, stream>>>(img_bf, capn_bf, nullptr, S);
    // 7. per-image Gram
    gram_rows<<<MROWS, 64, 0, stream>>>(img_emb, G);
    // 8. fused epilogue
    epilogue<<<dim3(NC, NI), 256, 0, stream>>>(S, G, w1, cap_lens, out);
}

// Round 3
// 196.557 us; speedup vs baseline: 2.3927x; 1.0993x over previous
//
#include <hip/hip_runtime.h>

// Problem constants (fixed by setup_inputs)
constexpr int NI = 64;    // images
constexpr int NC = 64;    // captions
constexpr int RR = 36;    // regions
constexpr int WW = 32;    // max words
constexpr int DI = 2048;  // img_dim
constexpr int DD = 1024;  // d
constexpr int MROWS = NI * RR;  // 2304
constexpr int NCOLS = NC * WW;  // 2048

#define EPSV 1e-8f
#define LAM_SM 9.0f
#define LAM_LSE 6.0f
#define LEAKY_S 0.1f

typedef __bf16 bf16x8 __attribute__((ext_vector_type(8)));
typedef float f32x4 __attribute__((ext_vector_type(4)));
typedef unsigned short ushort8v __attribute__((ext_vector_type(8)));
typedef unsigned short ushort4v __attribute__((ext_vector_type(4)));

__device__ __forceinline__ unsigned short f2bf(float f) {
    unsigned int u = __builtin_bit_cast(unsigned int, f);
    unsigned int r = (u + 0x7fffu + ((u >> 16) & 1u)) >> 16;
    return (unsigned short)r;
}

#define GLOAD16(gp, lp)                                                              \
    __builtin_amdgcn_global_load_lds(                                                \
        (const __attribute__((address_space(1))) unsigned int*)(gp),                 \
        (__attribute__((address_space(3))) unsigned int*)(lp), 16, 0, 0)

// ---------------- f32 -> bf16 bulk convert (8 elems/thread) ----------------
__global__ __launch_bounds__(256) void cvt_bf16(const float* __restrict__ X,
                                                unsigned short* __restrict__ Y, int n8)
{
    int i = blockIdx.x * 256 + threadIdx.x;
    if (i >= n8) return;
    const float4* X4 = reinterpret_cast<const float4*>(X);
    float4 a = X4[i * 2], b = X4[i * 2 + 1];
    ushort8v o;
    o[0] = f2bf(a.x); o[1] = f2bf(a.y); o[2] = f2bf(a.z); o[3] = f2bf(a.w);
    o[4] = f2bf(b.x); o[5] = f2bf(b.y); o[6] = f2bf(b.z); o[7] = f2bf(b.w);
    *reinterpret_cast<ushort8v*>(&Y[i * 8]) = o;
}

// ---------------- W_fc (2048x1024) f32 -> Wt (1024x2048) bf16 ----------------
__global__ __launch_bounds__(256) void transpose_cvt(const float* __restrict__ W,
                                                     unsigned short* __restrict__ Wt)
{
    __shared__ float t[32][33];
    const int bk = blockIdx.x * 32;  // k dim (2048)
    const int bn = blockIdx.y * 32;  // n dim (1024)
    const int x = threadIdx.x;       // 0..31
    for (int yy = threadIdx.y; yy < 32; yy += 8)
        t[yy][x] = W[(bk + yy) * DD + bn + x];
    __syncthreads();
    for (int yy = threadIdx.y; yy < 32; yy += 8)
        Wt[(bn + yy) * DI + bk + x] = f2bf(t[x][yy]);
}

// ---------------- MFMA GEMM: C(MxN f32) = A(MxK bf16) @ Bt(NxK bf16)^T [+bias] ----------------
// 64x128 tile, 4 waves (2x2), each wave 32x64 = 2x4 frags of 16x16x32.
// Grid coverage: gemm1 36x8=288 blocks, gemm2 36x16=576 (vs 144/288 at 128^2).
template <int M, int N, int K, bool BIAS>
__global__ __launch_bounds__(256) void gemm_mfma(const unsigned short* __restrict__ A,
                                                 const unsigned short* __restrict__ Bt,
                                                 const float* __restrict__ bias,
                                                 float* __restrict__ C)
{
    __shared__ __align__(16) unsigned short As[64 * 32];
    __shared__ __align__(16) unsigned short Bs[128 * 32];
    const int tid = threadIdx.x;
    const int w = tid >> 6, lane = tid & 63;
    const int bm = blockIdx.x * 64, bn = blockIdx.y * 128;
    const int wr = w >> 1, wc = w & 1;

    f32x4 acc[2][4] = {};

    // staging: thread -> row sr = tid>>2, k-offset sk = (tid&3)*8.
    // LDS elem offset sr*32+sk = w*512 + 8*lane -> wave-uniform base As+w*512, lane stride 16B. ✓
    const int sr = tid >> 2;
    const int sk = (tid & 3) * 8;
    const unsigned short* gA0 = &A[(bm + sr) * K + sk];
    const unsigned short* gB0 = &Bt[(bn + sr) * K + sk];
    unsigned short* lA0 = &As[w * 512];
    unsigned short* lB0 = &Bs[w * 512];

    const int kgrp = (lane >> 4) * 8;
    const int fr = lane & 15;

    for (int k0 = 0; k0 < K; k0 += 32) {
        __syncthreads();
        GLOAD16(gA0 + k0, lA0);                       // A rows 0..63
        GLOAD16(gB0 + k0, lB0);                       // B rows 0..63
        GLOAD16(gB0 + 64 * K + k0, lB0 + 2048);       // B rows 64..127
        __syncthreads();

        bf16x8 af[2], bf[4];
        #pragma unroll
        for (int mi = 0; mi < 2; ++mi)
            af[mi] = *reinterpret_cast<const bf16x8*>(&As[(wr * 32 + mi * 16 + fr) * 32 + kgrp]);
        #pragma unroll
        for (int ni = 0; ni < 4; ++ni)
            bf[ni] = *reinterpret_cast<const bf16x8*>(&Bs[(wc * 64 + ni * 16 + fr) * 32 + kgrp]);
        #pragma unroll
        for (int mi = 0; mi < 2; ++mi)
            #pragma unroll
            for (int ni = 0; ni < 4; ++ni)
                acc[mi][ni] = __builtin_amdgcn_mfma_f32_16x16x32_bf16(af[mi], bf[ni], acc[mi][ni], 0, 0, 0);
    }

    // C/D layout: col = lane&15, row = (lane>>4)*4 + reg  [m89 verified]
    const int cr0 = (lane >> 4) * 4, cc = lane & 15;
    #pragma unroll
    for (int mi = 0; mi < 2; ++mi) {
        int row0 = bm + wr * 32 + mi * 16 + cr0;
        #pragma unroll
        for (int ni = 0; ni < 4; ++ni) {
            int col = bn + wc * 64 + ni * 16 + cc;
            float bv = BIAS ? bias[col] : 0.f;
            #pragma unroll
            for (int r = 0; r < 4; ++r)
                C[(row0 + r) * N + col] = acc[mi][ni][r] + bv;
        }
    }
}

// ---------------- row l2norm in place + bf16 copy (rows of length 1024) ----------------
__global__ __launch_bounds__(256) void rownorm_1024_bf(float* __restrict__ X,
                                                       unsigned short* __restrict__ Xbf)
{
    const int row = blockIdx.x;
    float4 v = *reinterpret_cast<float4*>(&X[row * 1024 + threadIdx.x * 4]);
    float s = v.x * v.x + v.y * v.y + v.z * v.z + v.w * v.w;
    #pragma unroll
    for (int off = 32; off; off >>= 1) s += __shfl_down(s, off);
    __shared__ float ps[4];
    if ((threadIdx.x & 63) == 0) ps[threadIdx.x >> 6] = s;
    __syncthreads();
    float tot = ps[0] + ps[1] + ps[2] + ps[3];
    float inv = 1.0f / (sqrtf(tot) + EPSV);
    v.x *= inv; v.y *= inv; v.z *= inv; v.w *= inv;
    *reinterpret_cast<float4*>(&X[row * 1024 + threadIdx.x * 4]) = v;
    ushort4v o;
    o[0] = f2bf(v.x); o[1] = f2bf(v.y); o[2] = f2bf(v.z); o[3] = f2bf(v.w);
    *reinterpret_cast<ushort4v*>(&Xbf[row * 1024 + threadIdx.x * 4]) = o;
}

// ---------------- caption norm: Ybf = bf16(l2norm(X)), w1 = ||l2norm(X)|| ----------------
__global__ __launch_bounds__(256) void capnorm_bf(const float* __restrict__ X,
                                                  unsigned short* __restrict__ Ybf,
                                                  float* __restrict__ w1)
{
    const int row = blockIdx.x;
    float4 v = *reinterpret_cast<const float4*>(&X[row * 1024 + threadIdx.x * 4]);
    float s = v.x * v.x + v.y * v.y + v.z * v.z + v.w * v.w;
    #pragma unroll
    for (int off = 32; off; off >>= 1) s += __shfl_down(s, off);
    __shared__ float ps[4];
    if ((threadIdx.x & 63) == 0) ps[threadIdx.x >> 6] = s;
    __syncthreads();
    float tot = ps[0] + ps[1] + ps[2] + ps[3];
    float n = sqrtf(tot);
    float inv = 1.0f / (n + EPSV);
    v.x *= inv; v.y *= inv; v.z *= inv; v.w *= inv;
    ushort4v o;
    o[0] = f2bf(v.x); o[1] = f2bf(v.y); o[2] = f2bf(v.z); o[3] = f2bf(v.w);
    *reinterpret_cast<ushort4v*>(&Ybf[row * 1024 + threadIdx.x * 4]) = o;
    if (threadIdx.x == 0) w1[row] = n * inv;  // = ||normalized||
}

// ---------------- per-image Gram (symmetric): G[i][r][rp] = <emb[i,r], emb[i,rp]> ----------------
// block per (i,r), 2 waves; compute rp >= r only, write both halves.
__global__ __launch_bounds__(128) void gram_rows(const float* __restrict__ emb,
                                                 float* __restrict__ G)
{
    const int b = blockIdx.x;         // 0..2303
    const int i = b / RR, r = b % RR;
    const int wv = threadIdx.x >> 6;  // 0..1
    const int lane = threadIdx.x & 63;
    float a[16];
    const float* rowp = &emb[(i * RR + r) * DD + lane * 16];
    #pragma unroll
    for (int q = 0; q < 4; ++q) {
        float4 v = *reinterpret_cast<const float4*>(&rowp[q * 4]);
        a[q * 4 + 0] = v.x; a[q * 4 + 1] = v.y; a[q * 4 + 2] = v.z; a[q * 4 + 3] = v.w;
    }
    for (int rp = r + wv; rp < RR; rp += 2) {
        const float* bp = &emb[(i * RR + rp) * DD + lane * 16];
        float s = 0.f;
        #pragma unroll
        for (int q = 0; q < 4; ++q) {
            float4 v = *reinterpret_cast<const float4*>(&bp[q * 4]);
            s += a[q * 4 + 0] * v.x + a[q * 4 + 1] * v.y + a[q * 4 + 2] * v.z + a[q * 4 + 3] * v.w;
        }
        #pragma unroll
        for (int off = 32; off; off >>= 1) s += __shfl_xor(s, off);
        if (lane == 0) {
            G[(i * RR + r) * RR + rp] = s;
            G[(i * RR + rp) * RR + r] = s;
        }
    }
}

// ---------------- fused epilogue per (c, i) ----------------
// 256 threads = 8 r-groups (rg) x 32 w-lanes. Softmax denominator cancels in
// row_sim = (sum_r e_r S_rw) / (w1 * sqrt(e^T G e)), so we never normalize.
__global__ __launch_bounds__(256) void epilogue(const float* __restrict__ S,
                                                const float* __restrict__ G,
                                                const float* __restrict__ w1v,
                                                const int* __restrict__ cap_lens,
                                                float* __restrict__ out)
{
    const int c = blockIdx.x, i = blockIdx.y;
    const int tid = threadIdx.x;
    const int w = tid & 31;      // word lane
    const int rg = tid >> 5;     // r-group 0..7

    __shared__ float St[32 * 37];    // raw S, [w][r] stride 37 (odd -> conflict-free)
    __shared__ float A2t[32 * 40];   // unnormalized e, [w][r] stride 40 (16B-aligned rows)
    __shared__ float Gl[36 * 40];    // G, [r][rp] stride 40 (16B-aligned rows)
    __shared__ float pmax_s[4][32];
    __shared__ float pw12[4][32];
    __shared__ float pw2[4][32];

    const int len = cap_lens[c];

    // ---- load S (transposed to w-major) and G ----
    for (int r = rg; r < RR; r += 8)
        St[w * 37 + r] = S[(i * RR + r) * NCOLS + c * WW + w];   // coalesced over w
    for (int e = tid; e < RR * RR; e += 256)
        Gl[(e / RR) * 40 + (e % RR)] = G[i * RR * RR + e];
    __syncthreads();

    // ---- P1: leaky + mask + l2norm over w (per r); keep a1 in regs ----
    float a1own[5];
    float pm = -1e30f;
    #pragma unroll
    for (int j = 0; j < 5; ++j) {
        int r = rg + 8 * j;
        if (r < RR) {
            float v = St[w * 37 + r];
            v = v > 0.f ? v : LEAKY_S * v;
            v = (w < len) ? v : 0.f;
            float ss = v * v;
            #pragma unroll
            for (int m = 1; m <= 16; m <<= 1) ss += __shfl_xor(ss, m);  // sum over 32 w-lanes
            a1own[j] = v * (1.0f / (sqrtf(ss) + EPSV));
            pm = fmaxf(pm, a1own[j]);
        } else a1own[j] = 0.f;
    }
    // softmax max over r (per w): wave-pair combine then 4 partials via LDS
    pm = fmaxf(pm, __shfl_xor(pm, 32));
    if ((rg & 1) == 0) pmax_s[rg >> 1][w] = pm;
    __syncthreads();
    float m = fmaxf(fmaxf(pmax_s[0][w], pmax_s[1][w]), fmaxf(pmax_s[2][w], pmax_s[3][w]));

    // ---- P2: e = exp(9(a1-m)); partial w12 numerator (uses RAW S) ----
    float eown[5];
    float pw12v = 0.f;
    #pragma unroll
    for (int j = 0; j < 5; ++j) {
        int r = rg + 8 * j;
        if (r < RR) {
            float e = __expf(LAM_SM * (a1own[j] - m));
            eown[j] = e;
            A2t[w * 40 + r] = e;
            pw12v += e * St[w * 37 + r];
        } else eown[j] = 0.f;
    }
    pw12v += __shfl_xor(pw12v, 32);
    if ((rg & 1) == 0) pw12[rg >> 1][w] = pw12v;
    __syncthreads();

    // ---- P3: w2sq partial = sum_{r in own set} e[w][r] * (sum_rp e[w][rp] G[r][rp]) ----
    // e-row cached in registers (9 x float4); G rows read as wave-uniform float4 broadcasts.
    float4 e4[9];
    #pragma unroll
    for (int q = 0; q < 9; ++q)
        e4[q] = *reinterpret_cast<const float4*>(&A2t[w * 40 + q * 4]);
    float pw2v = 0.f;
    #pragma unroll
    for (int j = 0; j < 5; ++j) {
        int r = rg + 8 * j;
        if (r < RR) {
            float t = 0.f;
            #pragma unroll
            for (int q = 0; q < 9; ++q) {
                float4 g = *reinterpret_cast<const float4*>(&Gl[r * 40 + q * 4]);
                t += e4[q].x * g.x + e4[q].y * g.y + e4[q].z * g.z + e4[q].w * g.w;
            }
            pw2v += eown[j] * t;
        }
    }
    pw2v += __shfl_xor(pw2v, 32);
    if ((rg & 1) == 0) pw2[rg >> 1][w] = pw2v;
    __syncthreads();

    // ---- P4+P5: per-w row_sim, masked exp, LSE over words (wave 0 only) ----
    if (tid < 32) {
        float w12num = pw12[0][w] + pw12[1][w] + pw12[2][w] + pw12[3][w];
        float w2sq   = pw2[0][w] + pw2[1][w] + pw2[2][w] + pw2[3][w];
        float w2u = sqrtf(fmaxf(w2sq, 0.f));
        // denominator eps-clamp can never bind: e_max=1 -> w2sq >= G_diag ~= 1
        float rs = w12num / fmaxf(w1v[c * WW + w] * w2u, 1e-30f);
        float ew = (w < len) ? __expf(LAM_LSE * rs) : 0.f;
        #pragma unroll
        for (int m2 = 1; m2 <= 16; m2 <<= 1) ew += __shfl_xor(ew, m2);
        if (w == 0) out[i * NC + c] = logf(ew) / LAM_LSE;
    }
}

extern "C" void kernel_launch(void* const* d_in, const int* in_sizes, int n_in,
                              void* d_out, int out_size, void* d_ws, size_t ws_size,
                              hipStream_t stream)
{
    const float* images   = (const float*)d_in[0];
    const float* cap_emb  = (const float*)d_in[1];
    const float* W_fc     = (const float*)d_in[2];
    const float* b_fc     = (const float*)d_in[3];
    const int*   cap_lens = (const int*)d_in[4];
    float* out = (float*)d_out;

    char* ws = (char*)d_ws;
    float*          img_emb   = (float*)(ws);                        // 9,437,184
    unsigned short* images_bf = (unsigned short*)(ws + 9437184);     // 9,437,184
    unsigned short* Wt        = (unsigned short*)(ws + 18874368);    // 4,194,304
    float*          S         = (float*)(ws + 9437184);              // reuses region A
    unsigned short* img_bf    = (unsigned short*)(ws + 28311552);    // 4,718,592
    unsigned short* capn_bf   = (unsigned short*)(ws + 33030144);    // 4,194,304
    float*          G         = (float*)(ws + 37224448);             //   331,776
    float*          w1        = (float*)(ws + 37556224);             //     8,192

    cvt_bf16<<<MROWS * DI / 2048, 256, 0, stream>>>(images, images_bf, MROWS * DI / 8);
    transpose_cvt<<<dim3(DI / 32, DD / 32), dim3(32, 8), 0, stream>>>(W_fc, Wt);
    gemm_mfma<MROWS, DD, DI, true><<<dim3(MROWS / 64, DD / 128), 256, 0, stream>>>(images_bf, Wt, b_fc, img_emb);
    rownorm_1024_bf<<<MROWS, 256, 0, stream>>>(img_emb, img_bf);
    capnorm_bf<<<NCOLS, 256, 0, stream>>>(cap_emb, capn_bf, w1);
    gemm_mfma<MROWS, NCOLS, DD, false><<<dim3(MROWS / 64, NCOLS / 128), 256, 0, stream>>>(img_bf, capn_bf, nullptr, S);
    gram_rows<<<MROWS, 128, 0, stream>>>(img_emb, G);
    epilogue<<<dim3(NC, NI), 256, 0, stream>>>(S, G, w1, cap_lens, out);
}

// Round 4
// 192.829 us; speedup vs baseline: 2.4389x; 1.0193x over previous
//
#include <hip/hip_runtime.h>

// Problem constants (fixed by setup_inputs)
constexpr int NI = 64;    // images
constexpr int NC = 64;    // captions
constexpr int RR = 36;    // regions
constexpr int WW = 32;    // max words
constexpr int DI = 2048;  // img_dim
constexpr int DD = 1024;  // d
constexpr int MROWS = NI * RR;  // 2304
constexpr int NCOLS = NC * WW;  // 2048

#define EPSV 1e-8f
#define LAM_SM 9.0f
#define LAM_LSE 6.0f
#define LEAKY_S 0.1f

typedef __bf16 bf16x8 __attribute__((ext_vector_type(8)));
typedef float f32x4 __attribute__((ext_vector_type(4)));
typedef unsigned short ushort8v __attribute__((ext_vector_type(8)));
typedef unsigned short ushort4v __attribute__((ext_vector_type(4)));

__device__ __forceinline__ unsigned short f2bf(float f) {
    unsigned int u = __builtin_bit_cast(unsigned int, f);
    unsigned int r = (u + 0x7fffu + ((u >> 16) & 1u)) >> 16;
    return (unsigned short)r;
}

#define GLOAD16(gp, lp)                                                              \
    __builtin_amdgcn_global_load_lds(                                                \
        (const __attribute__((address_space(1))) unsigned int*)(gp),                 \
        (__attribute__((address_space(3))) unsigned int*)(lp), 16, 0, 0)

// ---------------- fused prep: images->bf16 | W_fc transpose->bf16 | capnorm ----------------
// blocks [0,2304): cvt images; [2304,4352): transpose W; [4352,6400): capnorm.
__global__ __launch_bounds__(256) void prep(const float* __restrict__ images,
                                            const float* __restrict__ W,
                                            const float* __restrict__ cap,
                                            unsigned short* __restrict__ images_bf,
                                            unsigned short* __restrict__ Wt,
                                            unsigned short* __restrict__ capn_bf,
                                            float* __restrict__ w1)
{
    const int b = blockIdx.x, tid = threadIdx.x;
    if (b < 2304) {
        // images f32 -> bf16, 8 elems/thread (2304*256*8 = 4,718,592 exact)
        int i = b * 256 + tid;
        const float4* X4 = reinterpret_cast<const float4*>(images);
        float4 a = X4[i * 2], c = X4[i * 2 + 1];
        ushort8v o;
        o[0] = f2bf(a.x); o[1] = f2bf(a.y); o[2] = f2bf(a.z); o[3] = f2bf(a.w);
        o[4] = f2bf(c.x); o[5] = f2bf(c.y); o[6] = f2bf(c.z); o[7] = f2bf(c.w);
        *reinterpret_cast<ushort8v*>(&images_bf[i * 8]) = o;
    } else if (b < 4352) {
        // W_fc (2048x1024) -> Wt (1024x2048) bf16
        __shared__ float t[32][33];
        int bi = b - 2304;
        int bk = (bi >> 5) * 32;   // 64 k-tiles
        int bn = (bi & 31) * 32;   // 32 n-tiles
        int x = tid & 31, y0 = tid >> 5;
        for (int yy = y0; yy < 32; yy += 8)
            t[yy][x] = W[(bk + yy) * DD + bn + x];
        __syncthreads();
        for (int yy = y0; yy < 32; yy += 8)
            Wt[(bn + yy) * DI + bk + x] = f2bf(t[x][yy]);
    } else {
        // caption row l2norm -> bf16 + w1
        int row = b - 4352;
        float4 v = *reinterpret_cast<const float4*>(&cap[row * 1024 + tid * 4]);
        float s = v.x * v.x + v.y * v.y + v.z * v.z + v.w * v.w;
        #pragma unroll
        for (int off = 32; off; off >>= 1) s += __shfl_down(s, off);
        __shared__ float ps[4];
        if ((tid & 63) == 0) ps[tid >> 6] = s;
        __syncthreads();
        float tot = ps[0] + ps[1] + ps[2] + ps[3];
        float n = sqrtf(tot);
        float inv = 1.0f / (n + EPSV);
        v.x *= inv; v.y *= inv; v.z *= inv; v.w *= inv;
        ushort4v o;
        o[0] = f2bf(v.x); o[1] = f2bf(v.y); o[2] = f2bf(v.z); o[3] = f2bf(v.w);
        *reinterpret_cast<ushort4v*>(&capn_bf[row * 1024 + tid * 4]) = o;
        if (tid == 0) w1[row] = n * inv;  // = ||normalized||
    }
}

// ---------------- MFMA GEMM (m97 structure): 128x128 tile, 4 waves, 4x4 frags ----------------
// C_z(MxN f32) = A(M x K/KS bf16 slice z) @ Bt(N x K/KS slice z)^T, z = blockIdx.z.
template <int M, int N, int K, int KS>
__global__ __launch_bounds__(256) void gemm_mfma(const unsigned short* __restrict__ A,
                                                 const unsigned short* __restrict__ Bt,
                                                 float* __restrict__ C)
{
    __shared__ __align__(16) unsigned short As[128 * 32];
    __shared__ __align__(16) unsigned short Bs[128 * 32];
    const int tid = threadIdx.x;
    const int w = tid >> 6, lane = tid & 63;
    const int bm = blockIdx.x * 128, bn = blockIdx.y * 128;
    const int z = blockIdx.z;
    const int klo = z * (K / KS), khi = klo + K / KS;
    const int wr = w >> 1, wc = w & 1;

    f32x4 acc[4][4] = {};

    // wave w stages rows [w*32, w*32+32): LDS elem = w*1024 + 8*lane (linear, 16B/lane). ✓
    const int sr = w * 32 + (lane >> 2);
    const int sk = (lane & 3) * 8;
    const unsigned short* gA0 = &A[(size_t)(bm + sr) * K + sk];
    const unsigned short* gB0 = &Bt[(size_t)(bn + sr) * K + sk];
    unsigned short* lA0 = &As[w * 1024];
    unsigned short* lB0 = &Bs[w * 1024];

    const int kgrp = (lane >> 4) * 8;
    const int fr = lane & 15;

    for (int k0 = klo; k0 < khi; k0 += 32) {
        __syncthreads();
        GLOAD16(gA0 + k0, lA0);
        GLOAD16(gA0 + 16 * K + k0, lA0 + 512);
        GLOAD16(gB0 + k0, lB0);
        GLOAD16(gB0 + 16 * K + k0, lB0 + 512);
        __syncthreads();

        bf16x8 af[4], bfv[4];
        #pragma unroll
        for (int mi = 0; mi < 4; ++mi)
            af[mi] = *reinterpret_cast<const bf16x8*>(&As[(wr * 64 + mi * 16 + fr) * 32 + kgrp]);
        #pragma unroll
        for (int ni = 0; ni < 4; ++ni)
            bfv[ni] = *reinterpret_cast<const bf16x8*>(&Bs[(wc * 64 + ni * 16 + fr) * 32 + kgrp]);
        #pragma unroll
        for (int mi = 0; mi < 4; ++mi)
            #pragma unroll
            for (int ni = 0; ni < 4; ++ni)
                acc[mi][ni] = __builtin_amdgcn_mfma_f32_16x16x32_bf16(af[mi], bfv[ni], acc[mi][ni], 0, 0, 0);
    }

    // C/D layout: col = lane&15, row = (lane>>4)*4 + reg  [m89 verified]
    float* Cz = C + (size_t)z * M * N;
    const int cr0 = (lane >> 4) * 4, cc = lane & 15;
    #pragma unroll
    for (int mi = 0; mi < 4; ++mi) {
        int row0 = bm + wr * 64 + mi * 16 + cr0;
        #pragma unroll
        for (int ni = 0; ni < 4; ++ni) {
            int col = bn + wc * 64 + ni * 16 + cc;
            #pragma unroll
            for (int r = 0; r < 4; ++r)
                Cz[(size_t)(row0 + r) * N + col] = acc[mi][ni][r];
        }
    }
}

// ---------------- rownorm: v = part0 + part1 + bias; l2norm; write f32 (in place) + bf16 ----------------
__global__ __launch_bounds__(256) void rownorm_add(float* __restrict__ P0,
                                                   const float* __restrict__ P1,
                                                   const float* __restrict__ bias,
                                                   unsigned short* __restrict__ Xbf)
{
    const int row = blockIdx.x;
    const int t4 = threadIdx.x * 4;
    float4 a = *reinterpret_cast<float4*>(&P0[row * 1024 + t4]);
    float4 b = *reinterpret_cast<const float4*>(&P1[row * 1024 + t4]);
    float4 c = *reinterpret_cast<const float4*>(&bias[t4]);
    float4 v = {a.x + b.x + c.x, a.y + b.y + c.y, a.z + b.z + c.z, a.w + b.w + c.w};
    float s = v.x * v.x + v.y * v.y + v.z * v.z + v.w * v.w;
    #pragma unroll
    for (int off = 32; off; off >>= 1) s += __shfl_down(s, off);
    __shared__ float ps[4];
    if ((threadIdx.x & 63) == 0) ps[threadIdx.x >> 6] = s;
    __syncthreads();
    float tot = ps[0] + ps[1] + ps[2] + ps[3];
    float inv = 1.0f / (sqrtf(tot) + EPSV);
    v.x *= inv; v.y *= inv; v.z *= inv; v.w *= inv;
    *reinterpret_cast<float4*>(&P0[row * 1024 + t4]) = v;
    ushort4v o;
    o[0] = f2bf(v.x); o[1] = f2bf(v.y); o[2] = f2bf(v.z); o[3] = f2bf(v.w);
    *reinterpret_cast<ushort4v*>(&Xbf[row * 1024 + t4]) = o;
}

// ---------------- per-image Gram (symmetric): G[i][r][rp] = <emb[i,r], emb[i,rp]> ----------------
__global__ __launch_bounds__(128) void gram_rows(const float* __restrict__ emb,
                                                 float* __restrict__ G)
{
    const int b = blockIdx.x;         // 0..2303
    const int i = b / RR, r = b % RR;
    const int wv = threadIdx.x >> 6;  // 0..1
    const int lane = threadIdx.x & 63;
    float a[16];
    const float* rowp = &emb[(i * RR + r) * DD + lane * 16];
    #pragma unroll
    for (int q = 0; q < 4; ++q) {
        float4 v = *reinterpret_cast<const float4*>(&rowp[q * 4]);
        a[q * 4 + 0] = v.x; a[q * 4 + 1] = v.y; a[q * 4 + 2] = v.z; a[q * 4 + 3] = v.w;
    }
    for (int rp = r + wv; rp < RR; rp += 2) {
        const float* bp = &emb[(i * RR + rp) * DD + lane * 16];
        float s = 0.f;
        #pragma unroll
        for (int q = 0; q < 4; ++q) {
            float4 v = *reinterpret_cast<const float4*>(&bp[q * 4]);
            s += a[q * 4 + 0] * v.x + a[q * 4 + 1] * v.y + a[q * 4 + 2] * v.z + a[q * 4 + 3] * v.w;
        }
        #pragma unroll
        for (int off = 32; off; off >>= 1) s += __shfl_xor(s, off);
        if (lane == 0) {
            G[(i * RR + r) * RR + rp] = s;
            G[(i * RR + rp) * RR + r] = s;
        }
    }
}

// ---------------- fused epilogue per (c, i) ----------------
// 256 threads = 8 r-groups (rg) x 32 w-lanes. Softmax denominator cancels in
// row_sim = (sum_r e_r S_rw) / (w1 * sqrt(e^T G e)), so we never normalize.
__global__ __launch_bounds__(256) void epilogue(const float* __restrict__ S,
                                                const float* __restrict__ G,
                                                const float* __restrict__ w1v,
                                                const int* __restrict__ cap_lens,
                                                float* __restrict__ out)
{
    const int c = blockIdx.x, i = blockIdx.y;
    const int tid = threadIdx.x;
    const int w = tid & 31;      // word lane
    const int rg = tid >> 5;     // r-group 0..7

    __shared__ float St[32 * 37];    // raw S, [w][r] stride 37
    __shared__ float A2t[32 * 36];   // unnormalized e, [w][r] stride 36 (4-way max on b128)
    __shared__ float Gl[36 * 36];    // G contiguous
    __shared__ float pmax_s[4][32];
    __shared__ float pw12[4][32];
    __shared__ float pw2[4][32];

    const int len = cap_lens[c];

    // ---- load S (transposed to w-major) and G ----
    for (int r = rg; r < RR; r += 8)
        St[w * 37 + r] = S[(i * RR + r) * NCOLS + c * WW + w];   // coalesced over w
    for (int e = tid; e < RR * RR; e += 256)
        Gl[e] = G[i * RR * RR + e];
    __syncthreads();

    // ---- P1: leaky + mask + l2norm over w (per r); keep a1 in regs ----
    float a1own[5];
    float pm = -1e30f;
    #pragma unroll
    for (int j = 0; j < 5; ++j) {
        int r = rg + 8 * j;
        if (r < RR) {
            float v = St[w * 37 + r];
            v = v > 0.f ? v : LEAKY_S * v;
            v = (w < len) ? v : 0.f;
            float ss = v * v;
            #pragma unroll
            for (int m = 1; m <= 16; m <<= 1) ss += __shfl_xor(ss, m);  // sum over 32 w-lanes
            a1own[j] = v * (1.0f / (sqrtf(ss) + EPSV));
            pm = fmaxf(pm, a1own[j]);
        } else a1own[j] = 0.f;
    }
    pm = fmaxf(pm, __shfl_xor(pm, 32));
    if ((rg & 1) == 0) pmax_s[rg >> 1][w] = pm;
    __syncthreads();
    float m = fmaxf(fmaxf(pmax_s[0][w], pmax_s[1][w]), fmaxf(pmax_s[2][w], pmax_s[3][w]));

    // ---- P2: e = exp(9(a1-m)); partial w12 numerator (uses RAW S) ----
    float eown[5];
    float pw12v = 0.f;
    #pragma unroll
    for (int j = 0; j < 5; ++j) {
        int r = rg + 8 * j;
        if (r < RR) {
            float e = __expf(LAM_SM * (a1own[j] - m));
            eown[j] = e;
            A2t[w * 36 + r] = e;
            pw12v += e * St[w * 37 + r];
        } else eown[j] = 0.f;
    }
    pw12v += __shfl_xor(pw12v, 32);
    if ((rg & 1) == 0) pw12[rg >> 1][w] = pw12v;
    __syncthreads();

    // ---- P3: w2sq partial = sum_{r in own set} e[w][r] * (sum_rp e[w][rp] G[r][rp]) ----
    float4 e4[9];
    #pragma unroll
    for (int q = 0; q < 9; ++q)
        e4[q] = *reinterpret_cast<const float4*>(&A2t[w * 36 + q * 4]);
    float pw2v = 0.f;
    #pragma unroll
    for (int j = 0; j < 5; ++j) {
        int r = rg + 8 * j;
        if (r < RR) {
            float t = 0.f;
            #pragma unroll
            for (int q = 0; q < 9; ++q) {
                float4 g = *reinterpret_cast<const float4*>(&Gl[r * 36 + q * 4]);
                t += e4[q].x * g.x + e4[q].y * g.y + e4[q].z * g.z + e4[q].w * g.w;
            }
            pw2v += eown[j] * t;
        }
    }
    pw2v += __shfl_xor(pw2v, 32);
    if ((rg & 1) == 0) pw2[rg >> 1][w] = pw2v;
    __syncthreads();

    // ---- P4+P5: per-w row_sim, masked exp, LSE over words (wave 0 only) ----
    if (tid < 32) {
        float w12num = pw12[0][w] + pw12[1][w] + pw12[2][w] + pw12[3][w];
        float w2sq   = pw2[0][w] + pw2[1][w] + pw2[2][w] + pw2[3][w];
        float w2u = sqrtf(fmaxf(w2sq, 0.f));
        float rs = w12num / fmaxf(w1v[c * WW + w] * w2u, 1e-30f);
        float ew = (w < len) ? __expf(LAM_LSE * rs) : 0.f;
        #pragma unroll
        for (int m2 = 1; m2 <= 16; m2 <<= 1) ew += __shfl_xor(ew, m2);
        if (w == 0) out[i * NC + c] = logf(ew) / LAM_LSE;
    }
}

extern "C" void kernel_launch(void* const* d_in, const int* in_sizes, int n_in,
                              void* d_out, int out_size, void* d_ws, size_t ws_size,
                              hipStream_t stream)
{
    const float* images   = (const float*)d_in[0];
    const float* cap_emb  = (const float*)d_in[1];
    const float* W_fc     = (const float*)d_in[2];
    const float* b_fc     = (const float*)d_in[3];
    const int*   cap_lens = (const int*)d_in[4];
    float* out = (float*)d_out;

    char* ws = (char*)d_ws;
    float*          part0     = (float*)(ws);                       //  9,437,184 (becomes img_emb f32)
    float*          part1     = (float*)(ws + 9437184);             //  9,437,184
    unsigned short* images_bf = (unsigned short*)(ws + 18874368);   //  9,437,184
    unsigned short* Wt        = (unsigned short*)(ws + 28311552);   //  4,194,304
    unsigned short* img_bf    = (unsigned short*)(ws + 32505856);   //  4,718,592
    unsigned short* capn_bf   = (unsigned short*)(ws + 37224448);   //  4,194,304
    float*          G         = (float*)(ws + 41418752);            //    331,776
    float*          w1        = (float*)(ws + 41750528);            //      8,192
    float*          S         = (float*)(ws + 41758720);            // 18,874,368

    // 1. fused prep: images->bf16 | Wt | capnorm(+w1)
    prep<<<6400, 256, 0, stream>>>(images, W_fc, cap_emb, images_bf, Wt, capn_bf, w1);
    // 2. split-K=2 projection GEMM: part_z = images @ W_fc (k-half z)
    gemm_mfma<MROWS, DD, DI, 2><<<dim3(MROWS / 128, DD / 128, 2), 256, 0, stream>>>(images_bf, Wt, part0);
    // 3. sum halves + bias, l2norm, write f32 (in place) + bf16
    rownorm_add<<<MROWS, 256, 0, stream>>>(part0, part1, b_fc, img_bf);
    // 4. S = img_emb @ capn^T
    gemm_mfma<MROWS, NCOLS, DD, 1><<<dim3(MROWS / 128, NCOLS / 128, 1), 256, 0, stream>>>(img_bf, capn_bf, S);
    // 5. per-image Gram (f32 normalized emb)
    gram_rows<<<MROWS, 128, 0, stream>>>(part0, G);
    // 6. fused epilogue
    epilogue<<<dim3(NC, NI), 256, 0, stream>>>(S, G, w1, cap_lens, out);
}

// Round 5
// 169.995 us; speedup vs baseline: 2.7665x; 1.1343x over previous
//
#include <hip/hip_runtime.h>

// Problem constants (fixed by setup_inputs)
constexpr int NI = 64;    // images
constexpr int NC = 64;    // captions
constexpr int RR = 36;    // regions
constexpr int WW = 32;    // max words
constexpr int DI = 2048;  // img_dim
constexpr int DD = 1024;  // d
constexpr int MROWS = NI * RR;  // 2304
constexpr int NCOLS = NC * WW;  // 2048

#define EPSV 1e-8f
#define LAM_SM 9.0f
#define LAM_LSE 6.0f
#define LEAKY_S 0.1f

typedef __bf16 bf16x8 __attribute__((ext_vector_type(8)));
typedef float f32x4 __attribute__((ext_vector_type(4)));
typedef unsigned short ushort8v __attribute__((ext_vector_type(8)));
typedef unsigned short ushort4v __attribute__((ext_vector_type(4)));

__device__ __forceinline__ unsigned short f2bf(float f) {
    unsigned int u = __builtin_bit_cast(unsigned int, f);
    unsigned int r = (u + 0x7fffu + ((u >> 16) & 1u)) >> 16;
    return (unsigned short)r;
}

#define GLOAD16(gp, lp)                                                              \
    __builtin_amdgcn_global_load_lds(                                                \
        (const __attribute__((address_space(1))) unsigned int*)(gp),                 \
        (__attribute__((address_space(3))) unsigned int*)(lp), 16, 0, 0)

// ---------------- fused prep: images->bf16 | W_fc transpose->bf16 | capnorm ----------------
__global__ __launch_bounds__(256) void prep(const float* __restrict__ images,
                                            const float* __restrict__ W,
                                            const float* __restrict__ cap,
                                            unsigned short* __restrict__ images_bf,
                                            unsigned short* __restrict__ Wt,
                                            unsigned short* __restrict__ capn_bf,
                                            float* __restrict__ w1)
{
    const int b = blockIdx.x, tid = threadIdx.x;
    if (b < 2304) {
        int i = b * 256 + tid;
        const float4* X4 = reinterpret_cast<const float4*>(images);
        float4 a = X4[i * 2], c = X4[i * 2 + 1];
        ushort8v o;
        o[0] = f2bf(a.x); o[1] = f2bf(a.y); o[2] = f2bf(a.z); o[3] = f2bf(a.w);
        o[4] = f2bf(c.x); o[5] = f2bf(c.y); o[6] = f2bf(c.z); o[7] = f2bf(c.w);
        *reinterpret_cast<ushort8v*>(&images_bf[i * 8]) = o;
    } else if (b < 4352) {
        __shared__ float t[32][33];
        int bi = b - 2304;
        int bk = (bi >> 5) * 32;
        int bn = (bi & 31) * 32;
        int x = tid & 31, y0 = tid >> 5;
        for (int yy = y0; yy < 32; yy += 8)
            t[yy][x] = W[(bk + yy) * DD + bn + x];
        __syncthreads();
        for (int yy = y0; yy < 32; yy += 8)
            Wt[(bn + yy) * DI + bk + x] = f2bf(t[x][yy]);
    } else {
        int row = b - 4352;
        float4 v = *reinterpret_cast<const float4*>(&cap[row * 1024 + tid * 4]);
        float s = v.x * v.x + v.y * v.y + v.z * v.z + v.w * v.w;
        #pragma unroll
        for (int off = 32; off; off >>= 1) s += __shfl_down(s, off);
        __shared__ float ps[4];
        if ((tid & 63) == 0) ps[tid >> 6] = s;
        __syncthreads();
        float tot = ps[0] + ps[1] + ps[2] + ps[3];
        float n = sqrtf(tot);
        float inv = 1.0f / (n + EPSV);
        v.x *= inv; v.y *= inv; v.z *= inv; v.w *= inv;
        ushort4v o;
        o[0] = f2bf(v.x); o[1] = f2bf(v.y); o[2] = f2bf(v.z); o[3] = f2bf(v.w);
        *reinterpret_cast<ushort4v*>(&capn_bf[row * 1024 + tid * 4]) = o;
        if (tid == 0) w1[row] = n * inv;
    }
}

// ---------------- projection GEMM: 64x128 tile, split-K; C_z = A @ Bt^T (k-slice z) ----------------
template <int M, int N, int K, int KS>
__global__ __launch_bounds__(256) void gemm_proj64(const unsigned short* __restrict__ A,
                                                   const unsigned short* __restrict__ Bt,
                                                   float* __restrict__ C)
{
    __shared__ __align__(16) unsigned short As[64 * 32];
    __shared__ __align__(16) unsigned short Bs[128 * 32];
    const int tid = threadIdx.x;
    const int w = tid >> 6, lane = tid & 63;
    const int bm = blockIdx.x * 64, bn = blockIdx.y * 128;
    const int z = blockIdx.z;
    const int klo = z * (K / KS);
    const int wr = w >> 1, wc = w & 1;

    f32x4 acc[2][4] = {};

    const int sr = tid >> 2;
    const int sk = (tid & 3) * 8;
    const unsigned short* gA0 = &A[(size_t)(bm + sr) * K + sk];
    const unsigned short* gB0 = &Bt[(size_t)(bn + sr) * K + sk];
    unsigned short* lA0 = &As[w * 512];
    unsigned short* lB0 = &Bs[w * 512];

    const int kgrp = (lane >> 4) * 8;
    const int fr = lane & 15;

    for (int k0 = klo; k0 < klo + K / KS; k0 += 32) {
        __syncthreads();
        GLOAD16(gA0 + k0, lA0);
        GLOAD16(gB0 + k0, lB0);
        GLOAD16(gB0 + 64 * K + k0, lB0 + 2048);
        __syncthreads();

        bf16x8 af[2], bfv[4];
        #pragma unroll
        for (int mi = 0; mi < 2; ++mi)
            af[mi] = *reinterpret_cast<const bf16x8*>(&As[(wr * 32 + mi * 16 + fr) * 32 + kgrp]);
        #pragma unroll
        for (int ni = 0; ni < 4; ++ni)
            bfv[ni] = *reinterpret_cast<const bf16x8*>(&Bs[(wc * 64 + ni * 16 + fr) * 32 + kgrp]);
        #pragma unroll
        for (int mi = 0; mi < 2; ++mi)
            #pragma unroll
            for (int ni = 0; ni < 4; ++ni)
                acc[mi][ni] = __builtin_amdgcn_mfma_f32_16x16x32_bf16(af[mi], bfv[ni], acc[mi][ni], 0, 0, 0);
    }

    float* Cz = C + (size_t)z * M * N;
    const int cr0 = (lane >> 4) * 4, cc = lane & 15;
    #pragma unroll
    for (int mi = 0; mi < 2; ++mi) {
        int row0 = bm + wr * 32 + mi * 16 + cr0;
        #pragma unroll
        for (int ni = 0; ni < 4; ++ni) {
            int col = bn + wc * 64 + ni * 16 + cc;
            #pragma unroll
            for (int r = 0; r < 4; ++r)
                Cz[(size_t)(row0 + r) * N + col] = acc[mi][ni][r];
        }
    }
}

// ---------------- rownorm: v = part0 + part1 + bias; l2norm; f32 (in place) + bf16 ----------------
__global__ __launch_bounds__(256) void rownorm_add(float* __restrict__ P0,
                                                   const float* __restrict__ P1,
                                                   const float* __restrict__ bias,
                                                   unsigned short* __restrict__ Xbf)
{
    const int row = blockIdx.x;
    const int t4 = threadIdx.x * 4;
    float4 a = *reinterpret_cast<float4*>(&P0[row * 1024 + t4]);
    float4 b = *reinterpret_cast<const float4*>(&P1[row * 1024 + t4]);
    float4 c = *reinterpret_cast<const float4*>(&bias[t4]);
    float4 v = {a.x + b.x + c.x, a.y + b.y + c.y, a.z + b.z + c.z, a.w + b.w + c.w};
    float s = v.x * v.x + v.y * v.y + v.z * v.z + v.w * v.w;
    #pragma unroll
    for (int off = 32; off; off >>= 1) s += __shfl_down(s, off);
    __shared__ float ps[4];
    if ((threadIdx.x & 63) == 0) ps[threadIdx.x >> 6] = s;
    __syncthreads();
    float tot = ps[0] + ps[1] + ps[2] + ps[3];
    float inv = 1.0f / (sqrtf(tot) + EPSV);
    v.x *= inv; v.y *= inv; v.z *= inv; v.w *= inv;
    *reinterpret_cast<float4*>(&P0[row * 1024 + t4]) = v;
    ushort4v o;
    o[0] = f2bf(v.x); o[1] = f2bf(v.y); o[2] = f2bf(v.z); o[3] = f2bf(v.w);
    *reinterpret_cast<ushort4v*>(&Xbf[row * 1024 + t4]) = o;
}

// ---------------- per-image Gram -> bf16, zero-padded cols to 64 ----------------
// block per (i,r), 2 waves; compute rp >= r, write both halves. G_bf[i][36][64].
__global__ __launch_bounds__(128) void gram_rows(const float* __restrict__ emb,
                                                 unsigned short* __restrict__ G_bf)
{
    const int b = blockIdx.x;
    const int i = b / RR, r = b % RR;
    const int wv = threadIdx.x >> 6;
    const int lane = threadIdx.x & 63;
    if (threadIdx.x < 28) G_bf[(size_t)(i * RR + r) * 64 + 36 + threadIdx.x] = 0;
    float a[16];
    const float* rowp = &emb[(i * RR + r) * DD + lane * 16];
    #pragma unroll
    for (int q = 0; q < 4; ++q) {
        float4 v = *reinterpret_cast<const float4*>(&rowp[q * 4]);
        a[q * 4 + 0] = v.x; a[q * 4 + 1] = v.y; a[q * 4 + 2] = v.z; a[q * 4 + 3] = v.w;
    }
    for (int rp = r + wv; rp < RR; rp += 2) {
        const float* bp = &emb[(i * RR + rp) * DD + lane * 16];
        float s = 0.f;
        #pragma unroll
        for (int q = 0; q < 4; ++q) {
            float4 v = *reinterpret_cast<const float4*>(&bp[q * 4]);
            s += a[q * 4 + 0] * v.x + a[q * 4 + 1] * v.y + a[q * 4 + 2] * v.z + a[q * 4 + 3] * v.w;
        }
        #pragma unroll
        for (int off = 32; off; off >>= 1) s += __shfl_xor(s, off);
        if (lane == 0) {
            unsigned short sb = f2bf(s);
            G_bf[(size_t)(i * RR + r) * 64 + rp] = sb;
            G_bf[(size_t)(i * RR + rp) * 64 + r] = sb;
        }
    }
}

// ---------------- fused S-GEMM + epilogue ----------------
// block = (cg, i): image i x captions [cg*4, cg*4+4). 4 waves; wave w = caption cg*4+w.
// GEMM: S(48x128) = img_rows(48, rows 36-47 garbage) @ capn(128 words)^T, K=1024.
// Then per-wave in-register epilogue; w2sq via T = G x E^T MFMA (bf16).
__global__ __launch_bounds__(256) void sim_fused(const unsigned short* __restrict__ img_bf,
                                                 const unsigned short* __restrict__ capn_bf,
                                                 const unsigned short* __restrict__ G_bf,
                                                 const float* __restrict__ w1v,
                                                 const int* __restrict__ cap_lens,
                                                 float* __restrict__ out)
{
    __shared__ __align__(16) unsigned short As[48 * 32];    // 3 KB
    __shared__ __align__(16) unsigned short Bs[128 * 32];   // 8 KB
    __shared__ __align__(16) unsigned short Gb[48 * 64];    // 6 KB, rows 36-47 zero
    __shared__ __align__(16) unsigned short Eb[4][32 * 64]; // 16 KB, cols 48-63 zero
    const int tid = threadIdx.x;
    const int w = tid >> 6, lane = tid & 63;
    const int i = blockIdx.y, cg = blockIdx.x;
    const int c = cg * 4 + w;
    const int hi = lane >> 4, lo = lane & 15;

    // stage Gb (rows 0..35 from G_bf, rows 36..47 zero); zero Eb cols 48..63
    {
        const unsigned int* gsrc = (const unsigned int*)(G_bf + (size_t)i * RR * 64);
        unsigned int* gdst = (unsigned int*)Gb;
        for (int e = tid; e < 36 * 32; e += 256) gdst[e] = gsrc[e];
        for (int e = tid; e < 12 * 32; e += 256) gdst[36 * 32 + e] = 0;
        unsigned int* ed = (unsigned int*)Eb;
        for (int e2 = tid; e2 < 4 * 32 * 8; e2 += 256) {
            int slab = e2 >> 8, rem = e2 & 255;
            int row = rem >> 3, q = rem & 7;
            ed[slab * 1024 + row * 32 + 24 + q] = 0;
        }
    }

    // ---- S GEMM ----
    f32x4 acc[3][2] = {};
    const unsigned short* gA0 = &img_bf[(size_t)(i * RR + (tid >> 2)) * DD + (tid & 3) * 8];
    const unsigned short* gB0 = &capn_bf[(size_t)(cg * 128 + (tid >> 2)) * DD + (tid & 3) * 8];
    unsigned short* lA0 = &As[w * 512];   // waves 0..2 only
    unsigned short* lB0 = &Bs[w * 512];
    const int kgrp = hi * 8;

    for (int k0 = 0; k0 < DD; k0 += 32) {
        __syncthreads();
        if (w < 3) GLOAD16(gA0 + k0, lA0);
        GLOAD16(gB0 + k0, lB0);
        GLOAD16(gB0 + 64 * DD + k0, lB0 + 2048);
        __syncthreads();
        bf16x8 b0 = *reinterpret_cast<const bf16x8*>(&Bs[(w * 32 + lo) * 32 + kgrp]);
        bf16x8 b1 = *reinterpret_cast<const bf16x8*>(&Bs[(w * 32 + 16 + lo) * 32 + kgrp]);
        #pragma unroll
        for (int mi = 0; mi < 3; ++mi) {
            bf16x8 af = *reinterpret_cast<const bf16x8*>(&As[(mi * 16 + lo) * 32 + kgrp]);
            acc[mi][0] = __builtin_amdgcn_mfma_f32_16x16x32_bf16(af, b0, acc[mi][0], 0, 0, 0);
            acc[mi][1] = __builtin_amdgcn_mfma_f32_16x16x32_bf16(af, b1, acc[mi][1], 0, 0, 0);
        }
    }
    // acc[mi][ni][reg] = S[r = mi*16 + hi*4 + reg][wcol = ni*16 + lo]

    const int len = cap_lens[c];

    // ---- P1: leaky+mask, l2norm over words (per r) ----
    float a1[3][2][4];
    #pragma unroll
    for (int mi = 0; mi < 3; ++mi)
        #pragma unroll
        for (int reg = 0; reg < 4; ++reg) {
            int r = mi * 16 + hi * 4 + reg;
            float v0 = acc[mi][0][reg]; v0 = v0 > 0.f ? v0 : LEAKY_S * v0; v0 = (lo < len) ? v0 : 0.f;
            float v1 = acc[mi][1][reg]; v1 = v1 > 0.f ? v1 : LEAKY_S * v1; v1 = (16 + lo < len) ? v1 : 0.f;
            float ss = v0 * v0 + v1 * v1;
            ss += __shfl_xor(ss, 1); ss += __shfl_xor(ss, 2);
            ss += __shfl_xor(ss, 4); ss += __shfl_xor(ss, 8);
            float inv = 1.0f / (sqrtf(ss) + EPSV);
            bool valid = r < RR;
            a1[mi][0][reg] = valid ? v0 * inv : -1e30f;
            a1[mi][1][reg] = valid ? v1 * inv : -1e30f;
        }

    // ---- P2: col max over r; e = exp(9(a1-m)); w12 partial; Eb write ----
    float m0 = -1e30f, m1 = -1e30f;
    #pragma unroll
    for (int mi = 0; mi < 3; ++mi)
        #pragma unroll
        for (int reg = 0; reg < 4; ++reg) {
            m0 = fmaxf(m0, a1[mi][0][reg]);
            m1 = fmaxf(m1, a1[mi][1][reg]);
        }
    m0 = fmaxf(m0, __shfl_xor(m0, 16)); m0 = fmaxf(m0, __shfl_xor(m0, 32));
    m1 = fmaxf(m1, __shfl_xor(m1, 16)); m1 = fmaxf(m1, __shfl_xor(m1, 32));

    float e_[3][2][4];
    float w12p0 = 0.f, w12p1 = 0.f;
    #pragma unroll
    for (int mi = 0; mi < 3; ++mi)
        #pragma unroll
        for (int reg = 0; reg < 4; ++reg) {
            int r = mi * 16 + hi * 4 + reg;
            bool valid = r < RR;
            float e0 = valid ? __expf(LAM_SM * (a1[mi][0][reg] - m0)) : 0.f;
            float e1 = valid ? __expf(LAM_SM * (a1[mi][1][reg] - m1)) : 0.f;
            e_[mi][0][reg] = e0; e_[mi][1][reg] = e1;
            w12p0 += e0 * acc[mi][0][reg];
            w12p1 += e1 * acc[mi][1][reg];
            Eb[w][(lo) * 64 + r] = f2bf(e0);
            Eb[w][(16 + lo) * 64 + r] = f2bf(e1);
        }
    w12p0 += __shfl_xor(w12p0, 16); w12p0 += __shfl_xor(w12p0, 32);
    w12p1 += __shfl_xor(w12p1, 16); w12p1 += __shfl_xor(w12p1, 32);
    __syncthreads();

    // ---- P3: T = G (48xK) x E^T (K x 32 words) via MFMA, K = 64 (padded) ----
    f32x4 T[3][2] = {};
    #pragma unroll
    for (int kk = 0; kk < 2; ++kk) {
        int kg2 = kk * 32 + hi * 8;
        bf16x8 eb0 = *reinterpret_cast<const bf16x8*>(&Eb[w][(lo) * 64 + kg2]);
        bf16x8 eb1 = *reinterpret_cast<const bf16x8*>(&Eb[w][(16 + lo) * 64 + kg2]);
        #pragma unroll
        for (int mi = 0; mi < 3; ++mi) {
            bf16x8 gf = *reinterpret_cast<const bf16x8*>(&Gb[(mi * 16 + lo) * 64 + kg2]);
            T[mi][0] = __builtin_amdgcn_mfma_f32_16x16x32_bf16(gf, eb0, T[mi][0], 0, 0, 0);
            T[mi][1] = __builtin_amdgcn_mfma_f32_16x16x32_bf16(gf, eb1, T[mi][1], 0, 0, 0);
        }
    }
    // w2sq = sum_r e * T   (garbage rows have e = 0)
    float w20 = 0.f, w21 = 0.f;
    #pragma unroll
    for (int mi = 0; mi < 3; ++mi)
        #pragma unroll
        for (int reg = 0; reg < 4; ++reg) {
            w20 += e_[mi][0][reg] * T[mi][0][reg];
            w21 += e_[mi][1][reg] * T[mi][1][reg];
        }
    w20 += __shfl_xor(w20, 16); w20 += __shfl_xor(w20, 32);
    w21 += __shfl_xor(w21, 16); w21 += __shfl_xor(w21, 32);

    // ---- P4+P5: row_sim, masked exp, LSE over words ----
    float ew = 0.f;
    if (lo < len) {
        float rs = w12p0 / fmaxf(w1v[c * WW + lo] * sqrtf(fmaxf(w20, 0.f)), 1e-30f);
        ew += __expf(LAM_LSE * rs);
    }
    if (16 + lo < len) {
        float rs = w12p1 / fmaxf(w1v[c * WW + 16 + lo] * sqrtf(fmaxf(w21, 0.f)), 1e-30f);
        ew += __expf(LAM_LSE * rs);
    }
    ew += __shfl_xor(ew, 1); ew += __shfl_xor(ew, 2);
    ew += __shfl_xor(ew, 4); ew += __shfl_xor(ew, 8);
    if (lane == 0) out[i * NC + c] = logf(ew) / LAM_LSE;
}

extern "C" void kernel_launch(void* const* d_in, const int* in_sizes, int n_in,
                              void* d_out, int out_size, void* d_ws, size_t ws_size,
                              hipStream_t stream)
{
    const float* images   = (const float*)d_in[0];
    const float* cap_emb  = (const float*)d_in[1];
    const float* W_fc     = (const float*)d_in[2];
    const float* b_fc     = (const float*)d_in[3];
    const int*   cap_lens = (const int*)d_in[4];
    float* out = (float*)d_out;

    char* ws = (char*)d_ws;
    float*          part0     = (float*)(ws);                       //  9,437,184 (becomes img_emb f32)
    float*          part1     = (float*)(ws + 9437184);             //  9,437,184
    unsigned short* images_bf = (unsigned short*)(ws + 18874368);   //  9,437,184
    unsigned short* Wt        = (unsigned short*)(ws + 28311552);   //  4,194,304
    unsigned short* img_bf    = (unsigned short*)(ws + 32505856);   //  4,718,592
    unsigned short* capn_bf   = (unsigned short*)(ws + 37224448);   //  4,194,304
    unsigned short* G_bf      = (unsigned short*)(ws + 41418752);   //    294,912
    float*          w1        = (float*)(ws + 41713664);            //      8,192

    // 1. fused prep: images->bf16 | Wt | capnorm(+w1)
    prep<<<6400, 256, 0, stream>>>(images, W_fc, cap_emb, images_bf, Wt, capn_bf, w1);
    // 2. split-K=2 projection GEMM, 64x128 tiles: part_z = images @ W_fc (k-half z)
    gemm_proj64<MROWS, DD, DI, 2><<<dim3(MROWS / 64, DD / 128, 2), 256, 0, stream>>>(images_bf, Wt, part0);
    // 3. sum halves + bias, l2norm, f32 (in place) + bf16
    rownorm_add<<<MROWS, 256, 0, stream>>>(part0, part1, b_fc, img_bf);
    // 4. per-image Gram -> bf16 padded
    gram_rows<<<MROWS, 128, 0, stream>>>(part0, G_bf);
    // 5. fused S-GEMM + epilogue
    sim_fused<<<dim3(16, NI), 256, 0, stream>>>(img_bf, capn_bf, G_bf, w1, cap_lens, out);
}

// Round 8
// 165.421 us; speedup vs baseline: 2.8430x; 1.0276x over previous
//
#include <hip/hip_runtime.h>

// Problem constants (fixed by setup_inputs)
constexpr int NI = 64;    // images
constexpr int NC = 64;    // captions
constexpr int RR = 36;    // regions
constexpr int WW = 32;    // max words
constexpr int DI = 2048;  // img_dim
constexpr int DD = 1024;  // d
constexpr int MROWS = NI * RR;  // 2304
constexpr int NCOLS = NC * WW;  // 2048

#define EPSV 1e-8f
#define LAM_SM 9.0f
#define LAM_LSE 6.0f
#define LEAKY_S 0.1f

typedef __bf16 bf16x8 __attribute__((ext_vector_type(8)));
typedef float f32x4 __attribute__((ext_vector_type(4)));
typedef unsigned short ushort8v __attribute__((ext_vector_type(8)));
typedef unsigned short ushort4v __attribute__((ext_vector_type(4)));

__device__ __forceinline__ unsigned short f2bf(float f) {
    unsigned int u = __builtin_bit_cast(unsigned int, f);
    unsigned int r = (u + 0x7fffu + ((u >> 16) & 1u)) >> 16;
    return (unsigned short)r;
}

#define GLOAD16(gp, lp)                                                              \
    __builtin_amdgcn_global_load_lds(                                                \
        (const __attribute__((address_space(1))) unsigned int*)(gp),                 \
        (__attribute__((address_space(3))) unsigned int*)(lp), 16, 0, 0)

// ---------------- fused prep: images->bf16 | W_fc transpose->bf16 | capnorm ----------------
__global__ __launch_bounds__(256) void prep(const float* __restrict__ images,
                                            const float* __restrict__ W,
                                            const float* __restrict__ cap,
                                            unsigned short* __restrict__ images_bf,
                                            unsigned short* __restrict__ Wt,
                                            unsigned short* __restrict__ capn_bf,
                                            float* __restrict__ w1)
{
    const int b = blockIdx.x, tid = threadIdx.x;
    if (b < 2304) {
        int i = b * 256 + tid;
        const float4* X4 = reinterpret_cast<const float4*>(images);
        float4 a = X4[i * 2], c = X4[i * 2 + 1];
        ushort8v o;
        o[0] = f2bf(a.x); o[1] = f2bf(a.y); o[2] = f2bf(a.z); o[3] = f2bf(a.w);
        o[4] = f2bf(c.x); o[5] = f2bf(c.y); o[6] = f2bf(c.z); o[7] = f2bf(c.w);
        *reinterpret_cast<ushort8v*>(&images_bf[i * 8]) = o;
    } else if (b < 4352) {
        __shared__ float t[32][33];
        int bi = b - 2304;
        int bk = (bi >> 5) * 32;
        int bn = (bi & 31) * 32;
        int x = tid & 31, y0 = tid >> 5;
        for (int yy = y0; yy < 32; yy += 8)
            t[yy][x] = W[(bk + yy) * DD + bn + x];
        __syncthreads();
        for (int yy = y0; yy < 32; yy += 8)
            Wt[(bn + yy) * DI + bk + x] = f2bf(t[x][yy]);
    } else {
        int row = b - 4352;
        float4 v = *reinterpret_cast<const float4*>(&cap[row * 1024 + tid * 4]);
        float s = v.x * v.x + v.y * v.y + v.z * v.z + v.w * v.w;
        #pragma unroll
        for (int off = 32; off; off >>= 1) s += __shfl_down(s, off);
        __shared__ float ps[4];
        if ((tid & 63) == 0) ps[tid >> 6] = s;
        __syncthreads();
        float tot = ps[0] + ps[1] + ps[2] + ps[3];
        float n = sqrtf(tot);
        float inv = 1.0f / (n + EPSV);
        v.x *= inv; v.y *= inv; v.z *= inv; v.w *= inv;
        ushort4v o;
        o[0] = f2bf(v.x); o[1] = f2bf(v.y); o[2] = f2bf(v.z); o[3] = f2bf(v.w);
        *reinterpret_cast<ushort4v*>(&capn_bf[row * 1024 + tid * 4]) = o;
        if (tid == 0) w1[row] = n * inv;
    }
}

// ---------------- projection GEMM: 64x128 tile, BK=64, XOR-swizzled LDS, split-K ----------------
// T2 swizzle per rule #21 (both-sides): LDS slot (row, j) holds global k-chunk
// j ^ (row&7); reader fetches chunk jj at slot jj ^ (row&7) (involution).
// GLOAD16 dest stays LINEAR (lane0 base + lane*16B); the permutation lives in
// the per-lane GLOBAL source address. Global coalescing preserved: 8 lanes of
// one row read the full 128B row segment in permuted chunk order.
template <int M, int N, int K, int KS>
__global__ __launch_bounds__(256) void gemm_proj64(const unsigned short* __restrict__ A,
                                                   const unsigned short* __restrict__ Bt,
                                                   float* __restrict__ C)
{
    __shared__ __align__(16) unsigned short As[64 * 64];   // 8 KB
    __shared__ __align__(16) unsigned short Bs[128 * 64];  // 16 KB
    const int tid = threadIdx.x;
    const int w = tid >> 6, lane = tid & 63;
    const int bm = blockIdx.x * 64, bn = blockIdx.y * 128;
    const int klo = blockIdx.z * (K / KS);
    const int wr = w >> 1, wc = w & 1;
    const int hi = lane >> 4, fr = lane & 15;

    f32x4 acc[2][4] = {};

    // staging: A slots s = tid, tid+256 (64 rows x 8 chunks); B slots tid + n*256 (128 rows)
    const unsigned short* gA[2];
    const unsigned short* gB[4];
    unsigned short* lA[2];
    unsigned short* lB[4];
    #pragma unroll
    for (int n = 0; n < 2; ++n) {
        int s = tid + n * 256;
        int row = s >> 3, j = (s & 7) ^ (row & 7);
        gA[n] = &A[(size_t)(bm + row) * K + klo + j * 8];
        lA[n] = &As[s * 8];
    }
    #pragma unroll
    for (int n = 0; n < 4; ++n) {
        int s = tid + n * 256;
        int row = s >> 3, j = (s & 7) ^ (row & 7);
        gB[n] = &Bt[(size_t)(bn + row) * K + klo + j * 8];
        lB[n] = &Bs[s * 8];
    }

    for (int k0 = 0; k0 < K / KS; k0 += 64) {
        __syncthreads();
        #pragma unroll
        for (int n = 0; n < 2; ++n) GLOAD16(gA[n] + k0, lA[n]);
        #pragma unroll
        for (int n = 0; n < 4; ++n) GLOAD16(gB[n] + k0, lB[n]);
        __syncthreads();
        #pragma unroll
        for (int ks = 0; ks < 2; ++ks) {
            bf16x8 af[2], bfv[4];
            #pragma unroll
            for (int mi = 0; mi < 2; ++mi) {
                int row = wr * 32 + mi * 16 + fr;
                af[mi] = *reinterpret_cast<const bf16x8*>(
                    &As[row * 64 + ((((ks << 2) + hi) ^ (row & 7)) << 3)]);
            }
            #pragma unroll
            for (int ni = 0; ni < 4; ++ni) {
                int row = wc * 64 + ni * 16 + fr;
                bfv[ni] = *reinterpret_cast<const bf16x8*>(
                    &Bs[row * 64 + ((((ks << 2) + hi) ^ (row & 7)) << 3)]);
            }
            #pragma unroll
            for (int mi = 0; mi < 2; ++mi)
                #pragma unroll
                for (int ni = 0; ni < 4; ++ni)
                    acc[mi][ni] = __builtin_amdgcn_mfma_f32_16x16x32_bf16(af[mi], bfv[ni], acc[mi][ni], 0, 0, 0);
        }
    }

    float* Cz = C + (size_t)blockIdx.z * M * N;
    const int cr0 = hi * 4, cc = fr;
    #pragma unroll
    for (int mi = 0; mi < 2; ++mi) {
        int row0 = bm + wr * 32 + mi * 16 + cr0;
        #pragma unroll
        for (int ni = 0; ni < 4; ++ni) {
            int col = bn + wc * 64 + ni * 16 + cc;
            #pragma unroll
            for (int r = 0; r < 4; ++r)
                Cz[(size_t)(row0 + r) * N + col] = acc[mi][ni][r];
        }
    }
}

// ---------------- rownorm: v = part0 + part1 + bias; l2norm; f32 (in place) + bf16 ----------------
__global__ __launch_bounds__(256) void rownorm_add(float* __restrict__ P0,
                                                   const float* __restrict__ P1,
                                                   const float* __restrict__ bias,
                                                   unsigned short* __restrict__ Xbf)
{
    const int row = blockIdx.x;
    const int t4 = threadIdx.x * 4;
    float4 a = *reinterpret_cast<float4*>(&P0[row * 1024 + t4]);
    float4 b = *reinterpret_cast<const float4*>(&P1[row * 1024 + t4]);
    float4 c = *reinterpret_cast<const float4*>(&bias[t4]);
    float4 v = {a.x + b.x + c.x, a.y + b.y + c.y, a.z + b.z + c.z, a.w + b.w + c.w};
    float s = v.x * v.x + v.y * v.y + v.z * v.z + v.w * v.w;
    #pragma unroll
    for (int off = 32; off; off >>= 1) s += __shfl_down(s, off);
    __shared__ float ps[4];
    if ((threadIdx.x & 63) == 0) ps[threadIdx.x >> 6] = s;
    __syncthreads();
    float tot = ps[0] + ps[1] + ps[2] + ps[3];
    float inv = 1.0f / (sqrtf(tot) + EPSV);
    v.x *= inv; v.y *= inv; v.z *= inv; v.w *= inv;
    *reinterpret_cast<float4*>(&P0[row * 1024 + t4]) = v;
    ushort4v o;
    o[0] = f2bf(v.x); o[1] = f2bf(v.y); o[2] = f2bf(v.z); o[3] = f2bf(v.w);
    *reinterpret_cast<ushort4v*>(&Xbf[row * 1024 + t4]) = o;
}

// ---------------- per-image Gram -> bf16, zero-padded cols to 64 (R5-proven) ----------------
__global__ __launch_bounds__(128) void gram_rows(const float* __restrict__ emb,
                                                 unsigned short* __restrict__ G_bf)
{
    const int b = blockIdx.x;
    const int i = b / RR, r = b % RR;
    const int wv = threadIdx.x >> 6;
    const int lane = threadIdx.x & 63;
    if (threadIdx.x < 28) G_bf[(size_t)(i * RR + r) * 64 + 36 + threadIdx.x] = 0;
    float a[16];
    const float* rowp = &emb[(i * RR + r) * DD + lane * 16];
    #pragma unroll
    for (int q = 0; q < 4; ++q) {
        float4 v = *reinterpret_cast<const float4*>(&rowp[q * 4]);
        a[q * 4 + 0] = v.x; a[q * 4 + 1] = v.y; a[q * 4 + 2] = v.z; a[q * 4 + 3] = v.w;
    }
    for (int rp = r + wv; rp < RR; rp += 2) {
        const float* bp = &emb[(i * RR + rp) * DD + lane * 16];
        float s = 0.f;
        #pragma unroll
        for (int q = 0; q < 4; ++q) {
            float4 v = *reinterpret_cast<const float4*>(&bp[q * 4]);
            s += a[q * 4 + 0] * v.x + a[q * 4 + 1] * v.y + a[q * 4 + 2] * v.z + a[q * 4 + 3] * v.w;
        }
        #pragma unroll
        for (int off = 32; off; off >>= 1) s += __shfl_xor(s, off);
        if (lane == 0) {
            unsigned short sb = f2bf(s);
            G_bf[(size_t)(i * RR + r) * 64 + rp] = sb;
            G_bf[(size_t)(i * RR + rp) * 64 + r] = sb;
        }
    }
}

// ---------------- fused S-GEMM + epilogue (R5 4-wave, byte-identical to the 170us pass) ----------------
__global__ __launch_bounds__(256) void sim_fused(const unsigned short* __restrict__ img_bf,
                                                 const unsigned short* __restrict__ capn_bf,
                                                 const unsigned short* __restrict__ G_bf,
                                                 const float* __restrict__ w1v,
                                                 const int* __restrict__ cap_lens,
                                                 float* __restrict__ out)
{
    __shared__ __align__(16) unsigned short As[48 * 32];    // 3 KB
    __shared__ __align__(16) unsigned short Bs[128 * 32];   // 8 KB
    __shared__ __align__(16) unsigned short Gb[48 * 64];    // 6 KB, rows 36-47 zero
    __shared__ __align__(16) unsigned short Eb[4][32 * 64]; // 16 KB, cols 48-63 zero
    const int tid = threadIdx.x;
    const int w = tid >> 6, lane = tid & 63;
    const int i = blockIdx.y, cg = blockIdx.x;
    const int c = cg * 4 + w;
    const int hi = lane >> 4, lo = lane & 15;

    // stage Gb (rows 0..35 from G_bf, rows 36..47 zero); zero Eb cols 48..63
    {
        const unsigned int* gsrc = (const unsigned int*)(G_bf + (size_t)i * RR * 64);
        unsigned int* gdst = (unsigned int*)Gb;
        for (int e = tid; e < 36 * 32; e += 256) gdst[e] = gsrc[e];
        for (int e = tid; e < 12 * 32; e += 256) gdst[36 * 32 + e] = 0;
        unsigned int* ed = (unsigned int*)Eb;
        for (int e2 = tid; e2 < 4 * 32 * 8; e2 += 256) {
            int slab = e2 >> 8, rem = e2 & 255;
            int row = rem >> 3, q = rem & 7;
            ed[slab * 1024 + row * 32 + 24 + q] = 0;
        }
    }

    // ---- S GEMM ----
    f32x4 acc[3][2] = {};
    const unsigned short* gA0 = &img_bf[(size_t)(i * RR + (tid >> 2)) * DD + (tid & 3) * 8];
    const unsigned short* gB0 = &capn_bf[(size_t)(cg * 128 + (tid >> 2)) * DD + (tid & 3) * 8];
    unsigned short* lA0 = &As[w * 512];   // waves 0..2 only
    unsigned short* lB0 = &Bs[w * 512];
    const int kgrp = hi * 8;

    for (int k0 = 0; k0 < DD; k0 += 32) {
        __syncthreads();
        if (w < 3) GLOAD16(gA0 + k0, lA0);
        GLOAD16(gB0 + k0, lB0);
        GLOAD16(gB0 + 64 * DD + k0, lB0 + 2048);
        __syncthreads();
        bf16x8 b0 = *reinterpret_cast<const bf16x8*>(&Bs[(w * 32 + lo) * 32 + kgrp]);
        bf16x8 b1 = *reinterpret_cast<const bf16x8*>(&Bs[(w * 32 + 16 + lo) * 32 + kgrp]);
        #pragma unroll
        for (int mi = 0; mi < 3; ++mi) {
            bf16x8 af = *reinterpret_cast<const bf16x8*>(&As[(mi * 16 + lo) * 32 + kgrp]);
            acc[mi][0] = __builtin_amdgcn_mfma_f32_16x16x32_bf16(af, b0, acc[mi][0], 0, 0, 0);
            acc[mi][1] = __builtin_amdgcn_mfma_f32_16x16x32_bf16(af, b1, acc[mi][1], 0, 0, 0);
        }
    }
    // acc[mi][ni][reg] = S[r = mi*16 + hi*4 + reg][wcol = ni*16 + lo]

    const int len = cap_lens[c];

    // ---- P1: leaky+mask, l2norm over words (per r) ----
    float a1[3][2][4];
    #pragma unroll
    for (int mi = 0; mi < 3; ++mi)
        #pragma unroll
        for (int reg = 0; reg < 4; ++reg) {
            int r = mi * 16 + hi * 4 + reg;
            float v0 = acc[mi][0][reg]; v0 = v0 > 0.f ? v0 : LEAKY_S * v0; v0 = (lo < len) ? v0 : 0.f;
            float v1 = acc[mi][1][reg]; v1 = v1 > 0.f ? v1 : LEAKY_S * v1; v1 = (16 + lo < len) ? v1 : 0.f;
            float ss = v0 * v0 + v1 * v1;
            ss += __shfl_xor(ss, 1); ss += __shfl_xor(ss, 2);
            ss += __shfl_xor(ss, 4); ss += __shfl_xor(ss, 8);
            float inv = 1.0f / (sqrtf(ss) + EPSV);
            bool valid = r < RR;
            a1[mi][0][reg] = valid ? v0 * inv : -1e30f;
            a1[mi][1][reg] = valid ? v1 * inv : -1e30f;
        }

    // ---- P2: col max over r; e = exp(9(a1-m)); w12 partial; Eb write ----
    float m0 = -1e30f, m1 = -1e30f;
    #pragma unroll
    for (int mi = 0; mi < 3; ++mi)
        #pragma unroll
        for (int reg = 0; reg < 4; ++reg) {
            m0 = fmaxf(m0, a1[mi][0][reg]);
            m1 = fmaxf(m1, a1[mi][1][reg]);
        }
    m0 = fmaxf(m0, __shfl_xor(m0, 16)); m0 = fmaxf(m0, __shfl_xor(m0, 32));
    m1 = fmaxf(m1, __shfl_xor(m1, 16)); m1 = fmaxf(m1, __shfl_xor(m1, 32));

    float e_[3][2][4];
    float w12p0 = 0.f, w12p1 = 0.f;
    #pragma unroll
    for (int mi = 0; mi < 3; ++mi)
        #pragma unroll
        for (int reg = 0; reg < 4; ++reg) {
            int r = mi * 16 + hi * 4 + reg;
            bool valid = r < RR;
            float e0 = valid ? __expf(LAM_SM * (a1[mi][0][reg] - m0)) : 0.f;
            float e1 = valid ? __expf(LAM_SM * (a1[mi][1][reg] - m1)) : 0.f;
            e_[mi][0][reg] = e0; e_[mi][1][reg] = e1;
            w12p0 += e0 * acc[mi][0][reg];
            w12p1 += e1 * acc[mi][1][reg];
            Eb[w][(lo) * 64 + r] = f2bf(e0);
            Eb[w][(16 + lo) * 64 + r] = f2bf(e1);
        }
    w12p0 += __shfl_xor(w12p0, 16); w12p0 += __shfl_xor(w12p0, 32);
    w12p1 += __shfl_xor(w12p1, 16); w12p1 += __shfl_xor(w12p1, 32);
    __syncthreads();

    // ---- P3: T = G (48xK) x E^T (K x 32 words) via MFMA, K = 64 (padded) ----
    f32x4 T[3][2] = {};
    #pragma unroll
    for (int kk = 0; kk < 2; ++kk) {
        int kg2 = kk * 32 + hi * 8;
        bf16x8 eb0 = *reinterpret_cast<const bf16x8*>(&Eb[w][(lo) * 64 + kg2]);
        bf16x8 eb1 = *reinterpret_cast<const bf16x8*>(&Eb[w][(16 + lo) * 64 + kg2]);
        #pragma unroll
        for (int mi = 0; mi < 3; ++mi) {
            bf16x8 gf = *reinterpret_cast<const bf16x8*>(&Gb[(mi * 16 + lo) * 64 + kg2]);
            T[mi][0] = __builtin_amdgcn_mfma_f32_16x16x32_bf16(gf, eb0, T[mi][0], 0, 0, 0);
            T[mi][1] = __builtin_amdgcn_mfma_f32_16x16x32_bf16(gf, eb1, T[mi][1], 0, 0, 0);
        }
    }
    // w2sq = sum_r e * T   (garbage rows have e = 0)
    float w20 = 0.f, w21 = 0.f;
    #pragma unroll
    for (int mi = 0; mi < 3; ++mi)
        #pragma unroll
        for (int reg = 0; reg < 4; ++reg) {
            w20 += e_[mi][0][reg] * T[mi][0][reg];
            w21 += e_[mi][1][reg] * T[mi][1][reg];
        }
    w20 += __shfl_xor(w20, 16); w20 += __shfl_xor(w20, 32);
    w21 += __shfl_xor(w21, 16); w21 += __shfl_xor(w21, 32);

    // ---- P4+P5: row_sim, masked exp, LSE over words ----
    float ew = 0.f;
    if (lo < len) {
        float rs = w12p0 / fmaxf(w1v[c * WW + lo] * sqrtf(fmaxf(w20, 0.f)), 1e-30f);
        ew += __expf(LAM_LSE * rs);
    }
    if (16 + lo < len) {
        float rs = w12p1 / fmaxf(w1v[c * WW + 16 + lo] * sqrtf(fmaxf(w21, 0.f)), 1e-30f);
        ew += __expf(LAM_LSE * rs);
    }
    ew += __shfl_xor(ew, 1); ew += __shfl_xor(ew, 2);
    ew += __shfl_xor(ew, 4); ew += __shfl_xor(ew, 8);
    if (lane == 0) out[i * NC + c] = logf(ew) / LAM_LSE;
}

extern "C" void kernel_launch(void* const* d_in, const int* in_sizes, int n_in,
                              void* d_out, int out_size, void* d_ws, size_t ws_size,
                              hipStream_t stream)
{
    const float* images   = (const float*)d_in[0];
    const float* cap_emb  = (const float*)d_in[1];
    const float* W_fc     = (const float*)d_in[2];
    const float* b_fc     = (const float*)d_in[3];
    const int*   cap_lens = (const int*)d_in[4];
    float* out = (float*)d_out;

    char* ws = (char*)d_ws;
    float*          part0     = (float*)(ws);                       //  9,437,184
    float*          part1     = (float*)(ws + 9437184);             //  9,437,184
    unsigned short* images_bf = (unsigned short*)(ws + 18874368);   //  9,437,184
    unsigned short* Wt        = (unsigned short*)(ws + 28311552);   //  4,194,304
    unsigned short* img_bf    = (unsigned short*)(ws + 32505856);   //  4,718,592
    unsigned short* capn_bf   = (unsigned short*)(ws + 37224448);   //  4,194,304 (absorbs 24KB garbage-row overrun reads)
    unsigned short* G_bf      = (unsigned short*)(ws + 41418752);   //    294,912
    float*          w1        = (float*)(ws + 41713664);            //      8,192

    // 1. fused prep: images->bf16 | Wt | capnorm(+w1)
    prep<<<6400, 256, 0, stream>>>(images, W_fc, cap_emb, images_bf, Wt, capn_bf, w1);
    // 2. split-K=2 projection GEMM, 64x128 tiles, BK=64 swizzled (isolated change vs R5)
    gemm_proj64<MROWS, DD, DI, 2><<<dim3(MROWS / 64, DD / 128, 2), 256, 0, stream>>>(images_bf, Wt, part0);
    // 3. sum halves + bias, l2norm, f32 (in place) + bf16
    rownorm_add<<<MROWS, 256, 0, stream>>>(part0, part1, b_fc, img_bf);
    // 4. per-image Gram -> bf16 padded
    gram_rows<<<MROWS, 128, 0, stream>>>(part0, G_bf);
    // 5. fused S-GEMM + epilogue (R5 4-wave exact)
    sim_fused<<<dim3(16, NI), 256, 0, stream>>>(img_bf, capn_bf, G_bf, w1, cap_lens, out);
}